// Round 16
// baseline (244.013 us; speedup 1.0000x reference)
//
#include <hip/hip_runtime.h>
#include <hip/hip_bf16.h>

#define N_ENT_C 100000
#define N_REL_C 500
#define NEDGE_C 500000
#define SCAN_BLOCKS 391   // ceil(100000/256)
#define EPB 1024          // edges per block for rel sort
#define NB_EDGE 489       // ceil(500000/1024)
#define CHUNK_B 62        // ceil(489/8)
#define MT_TOTAL 6250     // 100000/16 m-tiles, exact
#define MFMA4_GRID 512    // grid-stride m-loop
#define CVT_GRID 1563     // (unused; kept for reference)

// ---------------- ws layout (float offsets) — 15.25M < proven 25.7M -------------------
#define OFF_WTHI  0         // Wt hi bf16 [256][128] -> 16384 f32 slots
#define OFF_WTLO  16384
#define OFF_WTR   32768     // Wtr f32 [128][128]
#define OFF_PR    49152     // Pr f32 [500][128]
#define OFF_PRH   113152    // PrH bf16 [500][128]
#define OFF_QR    145920    // qr f32 [512]
#define OFF_QS    146432    // qs f32 [100000]   (atomic accum, zeroed)
#define OFF_QD    246432    // qd f32 [100000]   (atomic accum, zeroed)
#define OFF_OSRC  346432    // offsSrc [100000]
#define OFF_DRE   446432    // drE int4 [500000] {d,r,eb,-} = 2M ints (16B-aligned)
#define OFF_PSH   2446432   // PsH bf16 [100000][128]
#define OFF_PDH   8846432   // PdH bf16 [100000][128]
// end = 15,246,432 floats = 61 MB

// ---------------- d_out entity region (12.8M f32) as time-shared scratch --------------
#define DO_HSRC     0         // histSrc [100000]
#define DO_BSUM     100000    // blockSums [512]
#define DO_RELSTART 100512    // relStart [512]
#define DO_PART8    101024    // partial [8][512]
#define DO_CHUNKOFF 105120    // chunkOff [8][512]
#define DO_BLKHIST  109216    // blkHist [489][512]
#define DO_BLKOFFS  359584    // blockOffs [489][512]
#define DO_SDE      609952    // sdE int4 [500000] {s,d,eb,-} (16B-aligned)
#define DO_RELP     2609952   // relpart [4000][132] -> end 3,137,952 < 12.8M

typedef short bf16x8 __attribute__((ext_vector_type(8)));   // 8 bf16 = 16B = 4 VGPRs
typedef float f32x4  __attribute__((ext_vector_type(4)));
typedef float f32x2  __attribute__((ext_vector_type(2)));
typedef unsigned short u16x8 __attribute__((ext_vector_type(8)));

__device__ inline unsigned short bf_rne(float x) {
    unsigned int u = __float_as_uint(x);
    u += 0x7FFF + ((u >> 16) & 1);          // round-nearest-even
    return (unsigned short)(u >> 16);
}
__device__ inline float bf2f(unsigned short h) {
    return __uint_as_float(((unsigned int)h) << 16);
}
__device__ inline f32x2 bfpair(unsigned int w) {
    f32x2 r;
    r.x = __uint_as_float(w << 16);
    r.y = __uint_as_float(w & 0xFFFF0000u);
    return r;
}

// ---------------- weight prep ----------------
__global__ void prep_w(const float* __restrict__ aw, unsigned short* __restrict__ Wthi,
                       unsigned short* __restrict__ Wtlo, float* __restrict__ Wtr) {
    int idx = blockIdx.x * 256 + threadIdx.x;   // 0..49151
    if (idx < 32768) {
        int n = idx >> 7, k = idx & 127;
        float v = (n < 128) ? aw[n * 384 + k] : aw[(n - 128) * 384 + 128 + k];
        unsigned short h = bf_rne(v);
        Wthi[idx] = h;
        Wtlo[idx] = bf_rne(v - bf2f(h));
    } else if (idx < 49152) {
        int t = idx - 32768;
        int k = t >> 7, o = t & 127;
        Wtr[t] = aw[o * 384 + 256 + k];
    }
}

// ---------------- rel projection + qr epilogue ----------------
__global__ void rel_proj(const float* __restrict__ rele, const float* __restrict__ Wtr,
                         const float* __restrict__ ab, const float* __restrict__ a2w,
                         float* __restrict__ Pr, unsigned short* __restrict__ PrH,
                         float* __restrict__ qr) {
    int r = blockIdx.x;
    int o = threadIdx.x;
    float acc = ab[o];
    for (int k = 0; k < 128; ++k)
        acc = fmaf(rele[r * 128 + k], Wtr[k * 128 + o], acc);
    Pr[r * 128 + o] = acc;
    PrH[r * 128 + o] = bf_rne(acc);
    __shared__ float red[128];
    red[o] = acc * a2w[o];
    __syncthreads();
    for (int off = 64; off > 0; off >>= 1) {
        if (o < off) red[o] += red[o + off];
        __syncthreads();
    }
    if (o == 0) qr[r] = red[0];
}

// ---------------- ent projection: W in LDS, fused f32->bf16 hi/lo conversion ----------
// D = W · ent^T. 8 waves x 32 n-cols; W hi/lo in 128 KB LDS (16B slots XOR-swizzled).
// Each wave reads ent rows directly (f32), converts in regs (bit-identical to ent_cvt).
__global__ __launch_bounds__(512, 2) void ent_mfma5(const float* __restrict__ ent,
                                                    const unsigned short* __restrict__ Wthi,
                                                    const unsigned short* __restrict__ Wtlo,
                                                    const float* __restrict__ a2w,
                                                    unsigned short* __restrict__ PsH,
                                                    unsigned short* __restrict__ PdH,
                                                    float* __restrict__ qs,
                                                    float* __restrict__ qd) {
    __shared__ __align__(16) char shw[131072];   // Whi [0,64K), Wlo [64K,128K)
    const int tid = threadIdx.x;

    // stage W (once per block): 8192 16B-chunks, swizzled
#pragma unroll
    for (int it = 0; it < 16; ++it) {
        int g = it * 512 + tid;          // 0..8191
        int arr = g >> 12;               // 0 = hi, 1 = lo
        int gg = g & 4095;
        int n = gg >> 4, slot = gg & 15;
        const unsigned short* srcp = (arr ? Wtlo : Wthi) + n * 128 + slot * 8;
        uint4 v = *(const uint4*)srcp;
        *(uint4*)(shw + arr * 65536 + n * 256 + ((slot ^ (n & 7)) << 4)) = v;
    }
    __syncthreads();

    const int w = tid >> 6, lane = tid & 63;
    const int l15 = lane & 15, lh = lane >> 4;
    const int n0 = w * 32;

    float a2v[2][4];
#pragma unroll
    for (int nf = 0; nf < 2; ++nf)
#pragma unroll
        for (int v = 0; v < 4; ++v)
            a2v[nf][v] = a2w[(n0 + nf * 16 + lh * 4 + v) & 127];

    const bool isPs = (w < 4);
    unsigned short* PH = isPs ? PsH : PdH;
    float* qout = isPs ? qs : qd;
    const int colbase = (n0 & 127) + lh * 4;

    // per-lane LDS offsets for this wave's two n-rows
    int nA = n0 + l15, nB = n0 + 16 + l15;
    int offA = nA * 256, offB = nB * 256;
    int swzA = (nA & 7), swzB = (nB & 7);

    f32x4 zz = {0.f, 0.f, 0.f, 0.f};

    for (int mt = blockIdx.x; mt < MT_TOTAL; mt += MFMA4_GRID) {
        const int m = mt * 16 + l15;
        const float* rp = ent + (size_t)m * 128;
        // issue all 8 ent loads up front (one latency per tile)
        float4 e0[4], e1[4];
#pragma unroll
        for (int ks = 0; ks < 4; ++ks) {
            int kb = ks * 32 + lh * 8;
            e0[ks] = *(const float4*)(rp + kb);
            e1[ks] = *(const float4*)(rp + kb + 4);
        }

        f32x4 acc[2];
        acc[0] = zz; acc[1] = zz;
#pragma unroll
        for (int ks = 0; ks < 4; ++ks) {
            float f[8] = {e0[ks].x, e0[ks].y, e0[ks].z, e0[ks].w,
                          e1[ks].x, e1[ks].y, e1[ks].z, e1[ks].w};
            bf16x8 eh, el;
#pragma unroll
            for (int j = 0; j < 8; ++j) {
                unsigned short h = bf_rne(f[j]);
                eh[j] = (short)h;
                el[j] = (short)bf_rne(f[j] - bf2f(h));
            }
            int slot = ks * 4 + lh;
            int oA = offA + ((slot ^ swzA) << 4);
            int oB = offB + ((slot ^ swzB) << 4);
            bf16x8 whA = *(const bf16x8*)(shw + oA);
            bf16x8 wlA = *(const bf16x8*)(shw + 65536 + oA);
            bf16x8 whB = *(const bf16x8*)(shw + oB);
            bf16x8 wlB = *(const bf16x8*)(shw + 65536 + oB);
            acc[0] = __builtin_amdgcn_mfma_f32_16x16x32_bf16(whA, eh, acc[0], 0, 0, 0);
            acc[0] = __builtin_amdgcn_mfma_f32_16x16x32_bf16(whA, el, acc[0], 0, 0, 0);
            acc[0] = __builtin_amdgcn_mfma_f32_16x16x32_bf16(wlA, eh, acc[0], 0, 0, 0);
            acc[1] = __builtin_amdgcn_mfma_f32_16x16x32_bf16(whB, eh, acc[1], 0, 0, 0);
            acc[1] = __builtin_amdgcn_mfma_f32_16x16x32_bf16(whB, el, acc[1], 0, 0, 0);
            acc[1] = __builtin_amdgcn_mfma_f32_16x16x32_bf16(wlB, eh, acc[1], 0, 0, 0);
        }

        float qp = 0.f;
#pragma unroll
        for (int nf = 0; nf < 2; ++nf) {
            ushort4 st;
            st.x = bf_rne(acc[nf][0]);
            st.y = bf_rne(acc[nf][1]);
            st.z = bf_rne(acc[nf][2]);
            st.w = bf_rne(acc[nf][3]);
#pragma unroll
            for (int v = 0; v < 4; ++v) qp = fmaf(acc[nf][v], a2v[nf][v], qp);
            *(ushort4*)&PH[(size_t)m * 128 + colbase + nf * 16] = st;
        }
        qp += __shfl_xor(qp, 16);
        qp += __shfl_xor(qp, 32);
        if (lane < 16) unsafeAtomicAdd(&qout[m], qp);
    }
}

// ---------------- rel-key block histogram (LDS) + src global hist ----------------
__global__ __launch_bounds__(256) void edge_hist(const int* __restrict__ src,
                                                 const int* __restrict__ rel,
                                                 int* __restrict__ histSrc,
                                                 int* __restrict__ blkHist) {
    __shared__ int lh[512];
    int tid = threadIdx.x;
    lh[tid] = 0; lh[tid + 256] = 0;
    __syncthreads();
    int base = blockIdx.x * EPB;
#pragma unroll
    for (int j = 0; j < 4; ++j) {
        int e = base + j * 256 + tid;
        if (e < NEDGE_C) {
            atomicAdd(&histSrc[src[e]], 1);
            atomicAdd(&lh[rel[e]], 1);
        }
    }
    __syncthreads();
    blkHist[blockIdx.x * 512 + tid] = lh[tid];
    blkHist[blockIdx.x * 512 + 256 + tid] = lh[tid + 256];
}

__global__ void colsum(const int* __restrict__ blkHist, int* __restrict__ partial) {
    int r = threadIdx.x;
    int k = blockIdx.x;
    int b0 = k * CHUNK_B;
    int b1 = min(b0 + CHUNK_B, NB_EDGE);
    int t = 0;
    for (int b = b0; b < b1; ++b) t += blkHist[b * 512 + r];
    partial[k * 512 + r] = t;
}

__global__ void scan512(const int* __restrict__ partial, int* __restrict__ relStart,
                        int* __restrict__ chunkOff) {
    __shared__ int a[512], b2[512];
    int tid = threadIdx.x;
    int p8[8];
    int t = 0;
#pragma unroll
    for (int k = 0; k < 8; ++k) { p8[k] = partial[k * 512 + tid]; t += p8[k]; }
    a[tid] = t;
    __syncthreads();
    int v = t;
    int* cur = a; int* nxt = b2;
    for (int off = 1; off < 512; off <<= 1) {
        int x = cur[tid] + ((tid >= off) ? cur[tid - off] : 0);
        nxt[tid] = x;
        __syncthreads();
        int* tmp = cur; cur = nxt; nxt = tmp;
    }
    int excl = cur[tid] - v;
    relStart[tid] = excl;
    int run = excl;
#pragma unroll
    for (int k = 0; k < 8; ++k) { chunkOff[k * 512 + tid] = run; run += p8[k]; }
}

__global__ void colscan(const int* __restrict__ blkHist, const int* __restrict__ chunkOff,
                        int* __restrict__ blockOffs) {
    int r = threadIdx.x;
    int k = blockIdx.x;
    int b0 = k * CHUNK_B;
    int b1 = min(b0 + CHUNK_B, NB_EDGE);
    int off = chunkOff[k * 512 + r];
    for (int b = b0; b < b1; ++b) {
        blockOffs[b * 512 + r] = off;
        off += blkHist[b * 512 + r];
    }
}

__global__ void scan_blockred(const int* __restrict__ hist, int* __restrict__ blockSums, int n) {
    __shared__ int s[256];
    int tid = threadIdx.x;
    int i = blockIdx.x * 256 + tid;
    s[tid] = (i < n) ? hist[i] : 0;
    __syncthreads();
    for (int off = 128; off > 0; off >>= 1) {
        if (tid < off) s[tid] += s[tid + off];
        __syncthreads();
    }
    if (tid == 0) blockSums[blockIdx.x] = s[0];
}

__global__ void scan_single(int* __restrict__ data, int n) {
    __shared__ int a[1024], b2[1024];
    int tid = threadIdx.x;
    int v = (tid < n) ? data[tid] : 0;
    a[tid] = v;
    __syncthreads();
    int* cur = a; int* nxt = b2;
    for (int off = 1; off < 1024; off <<= 1) {
        int x = cur[tid] + ((tid >= off) ? cur[tid - off] : 0);
        nxt[tid] = x;
        __syncthreads();
        int* t = cur; cur = nxt; nxt = t;
    }
    if (tid < n) data[tid] = cur[tid] - v;   // exclusive
}

__global__ void scan_final(const int* __restrict__ hist, const int* __restrict__ blockOffs,
                           int* __restrict__ offs, int n) {
    __shared__ int a[256], b2[256];
    int tid = threadIdx.x;
    int i = blockIdx.x * 256 + tid;
    int v = (i < n) ? hist[i] : 0;
    a[tid] = v;
    __syncthreads();
    int* cur = a; int* nxt = b2;
    for (int off = 1; off < 256; off <<= 1) {
        int x = cur[tid] + ((tid >= off) ? cur[tid - off] : 0);
        nxt[tid] = x;
        __syncthreads();
        int* t = cur; cur = nxt; nxt = t;
    }
    if (i < n) offs[i] = cur[tid] - v + blockOffs[blockIdx.x];
}

// ---------------- scatter: int4 payloads {idx, idx, eb} + fast exp ----------------
__global__ __launch_bounds__(256) void scatter_both(const int* __restrict__ src,
                                                    const int* __restrict__ dst,
                                                    const int* __restrict__ rel,
                                                    int* __restrict__ offsSrc,
                                                    const int* __restrict__ blockOffs,
                                                    const float* __restrict__ qs,
                                                    const float* __restrict__ qd,
                                                    const float* __restrict__ qr,
                                                    const float* __restrict__ a2b,
                                                    int4* __restrict__ drE,
                                                    int4* __restrict__ sdE) {
    __shared__ int lh[512];
    int tid = threadIdx.x;
    lh[tid] = 0; lh[tid + 256] = 0;
    __syncthreads();
    float bb = a2b[0];
    int base = blockIdx.x * EPB;
    const int* bo = &blockOffs[blockIdx.x * 512];
#pragma unroll
    for (int j = 0; j < 4; ++j) {
        int e = base + j * 256 + tid;
        if (e < NEDGE_C) {
            int s = src[e], d = dst[e], r = rel[e];
            float b = qs[s] + qd[d] + qr[r] + bb;
            b = (b > 0.f) ? b : 0.01f * b;
            float eb = __expf(b);
            int ebi = __float_as_int(eb);
            int p = atomicAdd(&offsSrc[s], 1);
            drE[p] = make_int4(d, r, ebi, 0);
            int lr = atomicAdd(&lh[r], 1);
            sdE[bo[r] + lr] = make_int4(s, d, ebi, 0);
        }
    }
}

// ---------------- rel phase: 8 partial blocks per relation, pk unpack -----------------
__global__ __launch_bounds__(256) void rel_phase(const unsigned short* __restrict__ PsH,
                                                 const unsigned short* __restrict__ PdH,
                                                 const int* __restrict__ relStart,
                                                 const int4* __restrict__ sdE,
                                                 float* __restrict__ relpart) {
    int r = blockIdx.x >> 3;
    int p = blockIdx.x & 7;
    int start = relStart[r];
    int end = relStart[r + 1];
    int tid = threadIdx.x;
    int w = tid >> 6;
    int h = (tid >> 5) & 1;
    int l = tid & 31;
    int slot = p * 8 + w * 2 + h;
    f32x2 acc0 = {0.f, 0.f}, acc1 = {0.f, 0.f};
    float ebs = 0.f;
    for (int i = start + slot; i < end; i += 64) {
        int4 sd = sdE[i];
        int s = sd.x, d = sd.y;
        float eb = __int_as_float(sd.z);
        uint2 pw = *(const uint2*)&PsH[(size_t)s * 128 + l * 4];
        uint2 dw = *(const uint2*)&PdH[(size_t)d * 128 + l * 4];
        f32x2 ebp = {eb, eb};
        acc0 = ebp * (bfpair(pw.x) + bfpair(dw.x)) + acc0;
        acc1 = ebp * (bfpair(pw.y) + bfpair(dw.y)) + acc1;
        ebs += eb;
    }
    __shared__ float vred[8][128];
    __shared__ float sred[8];
    int sub = w * 2 + h;
    float4 accv = make_float4(acc0.x, acc0.y, acc1.x, acc1.y);
    *(float4*)&vred[sub][l * 4] = accv;
    if (l == 0) sred[sub] = ebs;
    __syncthreads();
    if (tid < 128) {
        float v = 0.f;
#pragma unroll
        for (int k2 = 0; k2 < 8; ++k2) v += vred[k2][tid];
        float e = 0.f;
#pragma unroll
        for (int k2 = 0; k2 < 8; ++k2) e += sred[k2];
        int pi = r * 8 + p;
        relpart[pi * 132 + tid] = v;
        if (tid == 0) relpart[pi * 132 + 128] = e;
    }
}

__global__ void rel_fin(const float* __restrict__ relpart, const float* __restrict__ Pr,
                        const int* __restrict__ relStart, float* __restrict__ outRel) {
    int r = blockIdx.x;
    int o = threadIdx.x;
    float v = 0.f, e = 0.f;
#pragma unroll
    for (int p = 0; p < 8; ++p) {
        v += relpart[(r * 8 + p) * 132 + o];
        e += relpart[(r * 8 + p) * 132 + 128];
    }
    float cnt = (float)(relStart[r + 1] - relStart[r]);
    float h = (v + e * Pr[r * 128 + o]) / fmaxf(cnt, 1.f);
    outRel[r * 128 + o] = (h > 0.f) ? h : (__expf(h) - 1.f);
}

// ---------------- src phase: 4 edges in flight, int4 record, pk unpack, fast exp ------
__global__ __launch_bounds__(256) void src_phase(const unsigned short* __restrict__ PsH,
                                                 const unsigned short* __restrict__ PdH,
                                                 const unsigned short* __restrict__ PrH,
                                                 const int* __restrict__ offsSrc,
                                                 const int4* __restrict__ drE,
                                                 float* __restrict__ out) {
    int wid = (blockIdx.x * 256 + threadIdx.x) >> 6;
    if (wid >= N_ENT_C) return;
    int lane = threadIdx.x & 63;
    int g = lane >> 4, l = lane & 15;   // 4 groups x 16 lanes; lane covers cols l*8..l*8+7
    int s = wid;
    int start = (s == 0) ? 0 : offsSrc[s - 1];
    int end = offsSrc[s];
    float* dstp = &out[(size_t)s * 128];
    if (end == start) {
        if (g == 0) {
            *(float4*)&dstp[l * 8] = make_float4(0.f, 0.f, 0.f, 0.f);
            *(float4*)&dstp[l * 8 + 4] = make_float4(0.f, 0.f, 0.f, 0.f);
        }
        return;
    }
    f32x2 accp[4];
#pragma unroll
    for (int j = 0; j < 4; ++j) accp[j] = (f32x2){0.f, 0.f};
    float ebs = 0.f;
    for (int i = start + g; i < end; i += 4) {
        int4 er = drE[i];
        int d = er.x, r = er.y;
        float eb = __int_as_float(er.z);
        uint4 dw = *(const uint4*)&PdH[(size_t)d * 128 + l * 8];
        uint4 rw = *(const uint4*)&PrH[(size_t)r * 128 + l * 8];
        f32x2 ebp = {eb, eb};
        accp[0] = ebp * (bfpair(dw.x) + bfpair(rw.x)) + accp[0];
        accp[1] = ebp * (bfpair(dw.y) + bfpair(rw.y)) + accp[1];
        accp[2] = ebp * (bfpair(dw.z) + bfpair(rw.z)) + accp[2];
        accp[3] = ebp * (bfpair(dw.w) + bfpair(rw.w)) + accp[3];
        ebs += eb;
    }
    float a8[8] = {accp[0].x, accp[0].y, accp[1].x, accp[1].y,
                   accp[2].x, accp[2].y, accp[3].x, accp[3].y};
#pragma unroll
    for (int j = 0; j < 8; ++j) {
        a8[j] += __shfl_xor(a8[j], 16);
        a8[j] += __shfl_xor(a8[j], 32);
    }
    ebs += __shfl_xor(ebs, 16);
    ebs += __shfl_xor(ebs, 32);
    if (g == 0) {
        float inv = 1.f / ebs;
        u16x8 ps = *(const u16x8*)&PsH[(size_t)s * 128 + l * 8];
        float h[8];
#pragma unroll
        for (int j = 0; j < 8; ++j) {
            float x = bf2f(ps[j]) + a8[j] * inv;
            h[j] = (x > 0.f) ? x : (__expf(x) - 1.f);
        }
        *(float4*)&dstp[l * 8]     = make_float4(h[0], h[1], h[2], h[3]);
        *(float4*)&dstp[l * 8 + 4] = make_float4(h[4], h[5], h[6], h[7]);
    }
}

extern "C" void kernel_launch(void* const* d_in, const int* in_sizes, int n_in,
                              void* d_out, int out_size, void* d_ws, size_t ws_size,
                              hipStream_t stream) {
    const float* ent  = (const float*)d_in[0];
    const float* rele = (const float*)d_in[1];
    const float* aw   = (const float*)d_in[2];
    const float* ab   = (const float*)d_in[3];
    const float* a2w  = (const float*)d_in[4];
    const float* a2b  = (const float*)d_in[5];
    const int* src    = (const int*)d_in[6];
    const int* dst    = (const int*)d_in[7];
    const int* rel    = (const int*)d_in[8];
    float* out = (float*)d_out;

    float* ws = (float*)d_ws;
    unsigned short* Wthi = (unsigned short*)(ws + OFF_WTHI);
    unsigned short* Wtlo = (unsigned short*)(ws + OFF_WTLO);
    float* Wtr = ws + OFF_WTR;
    float* Pr  = ws + OFF_PR;
    unsigned short* PrH = (unsigned short*)(ws + OFF_PRH);
    float* qr  = ws + OFF_QR;
    float* qs  = ws + OFF_QS;
    float* qd  = ws + OFF_QD;
    int* offsSrc = (int*)(ws + OFF_OSRC);
    int4* drE    = (int4*)(ws + OFF_DRE);
    unsigned short* PsH = (unsigned short*)(ws + OFF_PSH);
    unsigned short* PdH = (unsigned short*)(ws + OFF_PDH);

    int* dI = (int*)d_out;
    int* histSrc  = dI + DO_HSRC;
    int* bsum     = dI + DO_BSUM;
    int* relStart = dI + DO_RELSTART;
    int* part8    = dI + DO_PART8;
    int* chunkOff = dI + DO_CHUNKOFF;
    int* blkHist  = dI + DO_BLKHIST;
    int* blockOffs= dI + DO_BLKOFFS;
    int4* sdE     = (int4*)(dI + DO_SDE);
    float* relpart = (float*)dI + DO_RELP;

    hipMemsetAsync(ws + OFF_QR, 0, (size_t)(OFF_OSRC - OFF_QR) * sizeof(float), stream);

    prep_w<<<192, 256, 0, stream>>>(aw, Wthi, Wtlo, Wtr);
    rel_proj<<<N_REL_C, 128, 0, stream>>>(rele, Wtr, ab, a2w, Pr, PrH, qr);
    ent_mfma5<<<MFMA4_GRID, 512, 0, stream>>>(ent, Wthi, Wtlo, a2w, PsH, PdH, qs, qd);

    // d_out entity region used purely as sort scratch now
    hipMemsetAsync(histSrc, 0, (size_t)N_ENT_C * sizeof(int), stream);
    edge_hist<<<NB_EDGE, 256, 0, stream>>>(src, rel, histSrc, blkHist);
    colsum<<<8, 512, 0, stream>>>(blkHist, part8);
    scan512<<<1, 512, 0, stream>>>(part8, relStart, chunkOff);
    colscan<<<8, 512, 0, stream>>>(blkHist, chunkOff, blockOffs);
    scan_blockred<<<SCAN_BLOCKS, 256, 0, stream>>>(histSrc, bsum, N_ENT_C);
    scan_single<<<1, 1024, 0, stream>>>(bsum, SCAN_BLOCKS);
    scan_final<<<SCAN_BLOCKS, 256, 0, stream>>>(histSrc, bsum, offsSrc, N_ENT_C);
    scatter_both<<<NB_EDGE, 256, 0, stream>>>(src, dst, rel, offsSrc, blockOffs,
                                              qs, qd, qr, a2b, drE, sdE);

    rel_phase<<<N_REL_C * 8, 256, 0, stream>>>(PsH, PdH, relStart, sdE, relpart);
    rel_fin<<<N_REL_C, 128, 0, stream>>>(relpart, Pr, relStart, out + (size_t)N_ENT_C * 128);

    src_phase<<<(N_ENT_C + 3) / 4, 256, 0, stream>>>(PsH, PdH, PrH, offsSrc, drE, out);
}

// Round 17
// 243.634 us; speedup vs baseline: 1.0016x; 1.0016x over previous
//
#include <hip/hip_runtime.h>
#include <hip/hip_bf16.h>

#define N_ENT_C 100000
#define N_REL_C 500
#define NEDGE_C 500000
#define SCAN_BLOCKS 391   // ceil(100000/256)
#define EPB 1024          // edges per block for rel sort
#define NB_EDGE 489       // ceil(500000/1024)
#define CHUNK_B 62        // ceil(489/8)
#define MT_TOTAL 6250     // 100000/16 m-tiles, exact
#define MFMA4_GRID 512    // grid-stride m-loop
#define CVT_GRID 1563     // (unused; kept for reference)

// ---------------- ws layout (float offsets) — 15.25M < proven 25.7M -------------------
#define OFF_WTHI  0         // Wt hi bf16 [256][128] -> 16384 f32 slots
#define OFF_WTLO  16384
#define OFF_WTR   32768     // Wtr f32 [128][128]
#define OFF_PR    49152     // Pr f32 [500][128]
#define OFF_PRH   113152    // PrH bf16 [500][128]
#define OFF_QR    145920    // qr f32 [512]
#define OFF_QS    146432    // qs f32 [100000]   (atomic accum, zeroed)
#define OFF_QD    246432    // qd f32 [100000]   (atomic accum, zeroed)
#define OFF_OSRC  346432    // offsSrc [100000]
#define OFF_DRE   446432    // drE int4 [500000] {d,r,eb,-} = 2M ints (16B-aligned)
#define OFF_PSH   2446432   // PsH bf16 [100000][128]
#define OFF_PDH   8846432   // PdH bf16 [100000][128]
// end = 15,246,432 floats = 61 MB

// ---------------- d_out entity region (12.8M f32) as time-shared scratch --------------
#define DO_HSRC     0         // histSrc [100000]
#define DO_BSUM     100000    // blockSums [512]
#define DO_RELSTART 100512    // relStart [512]
#define DO_PART8    101024    // partial [8][512]
#define DO_CHUNKOFF 105120    // chunkOff [8][512]
#define DO_BLKHIST  109216    // blkHist [489][512]
#define DO_BLKOFFS  359584    // blockOffs [489][512]
#define DO_SDE      609952    // sdE int4 [500000] {s,d,eb,-} (16B-aligned)
#define DO_RELP     2609952   // relpart [4000][132] -> end 3,137,952 < 12.8M

typedef short bf16x8 __attribute__((ext_vector_type(8)));   // 8 bf16 = 16B = 4 VGPRs
typedef float f32x4  __attribute__((ext_vector_type(4)));
typedef float f32x2  __attribute__((ext_vector_type(2)));
typedef unsigned short u16x8 __attribute__((ext_vector_type(8)));

__device__ inline unsigned short bf_rne(float x) {
    unsigned int u = __float_as_uint(x);
    u += 0x7FFF + ((u >> 16) & 1);          // round-nearest-even
    return (unsigned short)(u >> 16);
}
__device__ inline float bf2f(unsigned short h) {
    return __uint_as_float(((unsigned int)h) << 16);
}
__device__ inline f32x2 bfpair(unsigned int w) {
    f32x2 r;
    r.x = __uint_as_float(w << 16);
    r.y = __uint_as_float(w & 0xFFFF0000u);
    return r;
}

// ---------------- weight prep ----------------
__global__ void prep_w(const float* __restrict__ aw, unsigned short* __restrict__ Wthi,
                       unsigned short* __restrict__ Wtlo, float* __restrict__ Wtr) {
    int idx = blockIdx.x * 256 + threadIdx.x;   // 0..49151
    if (idx < 32768) {
        int n = idx >> 7, k = idx & 127;
        float v = (n < 128) ? aw[n * 384 + k] : aw[(n - 128) * 384 + 128 + k];
        unsigned short h = bf_rne(v);
        Wthi[idx] = h;
        Wtlo[idx] = bf_rne(v - bf2f(h));
    } else if (idx < 49152) {
        int t = idx - 32768;
        int k = t >> 7, o = t & 127;
        Wtr[t] = aw[o * 384 + 256 + k];
    }
}

// ---------------- rel projection + qr epilogue ----------------
__global__ void rel_proj(const float* __restrict__ rele, const float* __restrict__ Wtr,
                         const float* __restrict__ ab, const float* __restrict__ a2w,
                         float* __restrict__ Pr, unsigned short* __restrict__ PrH,
                         float* __restrict__ qr) {
    int r = blockIdx.x;
    int o = threadIdx.x;
    float acc = ab[o];
    for (int k = 0; k < 128; ++k)
        acc = fmaf(rele[r * 128 + k], Wtr[k * 128 + o], acc);
    Pr[r * 128 + o] = acc;
    PrH[r * 128 + o] = bf_rne(acc);
    __shared__ float red[128];
    red[o] = acc * a2w[o];
    __syncthreads();
    for (int off = 64; off > 0; off >>= 1) {
        if (o < off) red[o] += red[o + off];
        __syncthreads();
    }
    if (o == 0) qr[r] = red[0];
}

// ---------------- ent projection: W in LDS, fused f32->bf16 hi/lo conversion ----------
// D = W · ent^T. 8 waves x 32 n-cols; W hi/lo in 128 KB LDS (16B slots XOR-swizzled).
// Each wave reads ent rows directly (f32), converts in regs (bit-identical to ent_cvt).
__global__ __launch_bounds__(512, 2) void ent_mfma5(const float* __restrict__ ent,
                                                    const unsigned short* __restrict__ Wthi,
                                                    const unsigned short* __restrict__ Wtlo,
                                                    const float* __restrict__ a2w,
                                                    unsigned short* __restrict__ PsH,
                                                    unsigned short* __restrict__ PdH,
                                                    float* __restrict__ qs,
                                                    float* __restrict__ qd) {
    __shared__ __align__(16) char shw[131072];   // Whi [0,64K), Wlo [64K,128K)
    const int tid = threadIdx.x;

    // stage W (once per block): 8192 16B-chunks, swizzled
#pragma unroll
    for (int it = 0; it < 16; ++it) {
        int g = it * 512 + tid;          // 0..8191
        int arr = g >> 12;               // 0 = hi, 1 = lo
        int gg = g & 4095;
        int n = gg >> 4, slot = gg & 15;
        const unsigned short* srcp = (arr ? Wtlo : Wthi) + n * 128 + slot * 8;
        uint4 v = *(const uint4*)srcp;
        *(uint4*)(shw + arr * 65536 + n * 256 + ((slot ^ (n & 7)) << 4)) = v;
    }
    __syncthreads();

    const int w = tid >> 6, lane = tid & 63;
    const int l15 = lane & 15, lh = lane >> 4;
    const int n0 = w * 32;

    float a2v[2][4];
#pragma unroll
    for (int nf = 0; nf < 2; ++nf)
#pragma unroll
        for (int v = 0; v < 4; ++v)
            a2v[nf][v] = a2w[(n0 + nf * 16 + lh * 4 + v) & 127];

    const bool isPs = (w < 4);
    unsigned short* PH = isPs ? PsH : PdH;
    float* qout = isPs ? qs : qd;
    const int colbase = (n0 & 127) + lh * 4;

    // per-lane LDS offsets for this wave's two n-rows
    int nA = n0 + l15, nB = n0 + 16 + l15;
    int offA = nA * 256, offB = nB * 256;
    int swzA = (nA & 7), swzB = (nB & 7);

    f32x4 zz = {0.f, 0.f, 0.f, 0.f};

    for (int mt = blockIdx.x; mt < MT_TOTAL; mt += MFMA4_GRID) {
        const int m = mt * 16 + l15;
        const float* rp = ent + (size_t)m * 128;
        // issue all 8 ent loads up front (one latency per tile)
        float4 e0[4], e1[4];
#pragma unroll
        for (int ks = 0; ks < 4; ++ks) {
            int kb = ks * 32 + lh * 8;
            e0[ks] = *(const float4*)(rp + kb);
            e1[ks] = *(const float4*)(rp + kb + 4);
        }

        f32x4 acc[2];
        acc[0] = zz; acc[1] = zz;
#pragma unroll
        for (int ks = 0; ks < 4; ++ks) {
            float f[8] = {e0[ks].x, e0[ks].y, e0[ks].z, e0[ks].w,
                          e1[ks].x, e1[ks].y, e1[ks].z, e1[ks].w};
            bf16x8 eh, el;
#pragma unroll
            for (int j = 0; j < 8; ++j) {
                unsigned short h = bf_rne(f[j]);
                eh[j] = (short)h;
                el[j] = (short)bf_rne(f[j] - bf2f(h));
            }
            int slot = ks * 4 + lh;
            int oA = offA + ((slot ^ swzA) << 4);
            int oB = offB + ((slot ^ swzB) << 4);
            bf16x8 whA = *(const bf16x8*)(shw + oA);
            bf16x8 wlA = *(const bf16x8*)(shw + 65536 + oA);
            bf16x8 whB = *(const bf16x8*)(shw + oB);
            bf16x8 wlB = *(const bf16x8*)(shw + 65536 + oB);
            acc[0] = __builtin_amdgcn_mfma_f32_16x16x32_bf16(whA, eh, acc[0], 0, 0, 0);
            acc[0] = __builtin_amdgcn_mfma_f32_16x16x32_bf16(whA, el, acc[0], 0, 0, 0);
            acc[0] = __builtin_amdgcn_mfma_f32_16x16x32_bf16(wlA, eh, acc[0], 0, 0, 0);
            acc[1] = __builtin_amdgcn_mfma_f32_16x16x32_bf16(whB, eh, acc[1], 0, 0, 0);
            acc[1] = __builtin_amdgcn_mfma_f32_16x16x32_bf16(whB, el, acc[1], 0, 0, 0);
            acc[1] = __builtin_amdgcn_mfma_f32_16x16x32_bf16(wlB, eh, acc[1], 0, 0, 0);
        }

        float qp = 0.f;
#pragma unroll
        for (int nf = 0; nf < 2; ++nf) {
            ushort4 st;
            st.x = bf_rne(acc[nf][0]);
            st.y = bf_rne(acc[nf][1]);
            st.z = bf_rne(acc[nf][2]);
            st.w = bf_rne(acc[nf][3]);
#pragma unroll
            for (int v = 0; v < 4; ++v) qp = fmaf(acc[nf][v], a2v[nf][v], qp);
            *(ushort4*)&PH[(size_t)m * 128 + colbase + nf * 16] = st;
        }
        qp += __shfl_xor(qp, 16);
        qp += __shfl_xor(qp, 32);
        if (lane < 16) unsafeAtomicAdd(&qout[m], qp);
    }
}

// ---------------- rel-key block histogram (LDS) + src global hist ----------------
__global__ __launch_bounds__(256) void edge_hist(const int* __restrict__ src,
                                                 const int* __restrict__ rel,
                                                 int* __restrict__ histSrc,
                                                 int* __restrict__ blkHist) {
    __shared__ int lh[512];
    int tid = threadIdx.x;
    lh[tid] = 0; lh[tid + 256] = 0;
    __syncthreads();
    int base = blockIdx.x * EPB;
#pragma unroll
    for (int j = 0; j < 4; ++j) {
        int e = base + j * 256 + tid;
        if (e < NEDGE_C) {
            atomicAdd(&histSrc[src[e]], 1);
            atomicAdd(&lh[rel[e]], 1);
        }
    }
    __syncthreads();
    blkHist[blockIdx.x * 512 + tid] = lh[tid];
    blkHist[blockIdx.x * 512 + 256 + tid] = lh[tid + 256];
}

__global__ void colsum(const int* __restrict__ blkHist, int* __restrict__ partial) {
    int r = threadIdx.x;
    int k = blockIdx.x;
    int b0 = k * CHUNK_B;
    int b1 = min(b0 + CHUNK_B, NB_EDGE);
    int t = 0;
    for (int b = b0; b < b1; ++b) t += blkHist[b * 512 + r];
    partial[k * 512 + r] = t;
}

__global__ void scan512(const int* __restrict__ partial, int* __restrict__ relStart,
                        int* __restrict__ chunkOff) {
    __shared__ int a[512], b2[512];
    int tid = threadIdx.x;
    int p8[8];
    int t = 0;
#pragma unroll
    for (int k = 0; k < 8; ++k) { p8[k] = partial[k * 512 + tid]; t += p8[k]; }
    a[tid] = t;
    __syncthreads();
    int v = t;
    int* cur = a; int* nxt = b2;
    for (int off = 1; off < 512; off <<= 1) {
        int x = cur[tid] + ((tid >= off) ? cur[tid - off] : 0);
        nxt[tid] = x;
        __syncthreads();
        int* tmp = cur; cur = nxt; nxt = tmp;
    }
    int excl = cur[tid] - v;
    relStart[tid] = excl;
    int run = excl;
#pragma unroll
    for (int k = 0; k < 8; ++k) { chunkOff[k * 512 + tid] = run; run += p8[k]; }
}

__global__ void colscan(const int* __restrict__ blkHist, const int* __restrict__ chunkOff,
                        int* __restrict__ blockOffs) {
    int r = threadIdx.x;
    int k = blockIdx.x;
    int b0 = k * CHUNK_B;
    int b1 = min(b0 + CHUNK_B, NB_EDGE);
    int off = chunkOff[k * 512 + r];
    for (int b = b0; b < b1; ++b) {
        blockOffs[b * 512 + r] = off;
        off += blkHist[b * 512 + r];
    }
}

__global__ void scan_blockred(const int* __restrict__ hist, int* __restrict__ blockSums, int n) {
    __shared__ int s[256];
    int tid = threadIdx.x;
    int i = blockIdx.x * 256 + tid;
    s[tid] = (i < n) ? hist[i] : 0;
    __syncthreads();
    for (int off = 128; off > 0; off >>= 1) {
        if (tid < off) s[tid] += s[tid + off];
        __syncthreads();
    }
    if (tid == 0) blockSums[blockIdx.x] = s[0];
}

__global__ void scan_single(int* __restrict__ data, int n) {
    __shared__ int a[1024], b2[1024];
    int tid = threadIdx.x;
    int v = (tid < n) ? data[tid] : 0;
    a[tid] = v;
    __syncthreads();
    int* cur = a; int* nxt = b2;
    for (int off = 1; off < 1024; off <<= 1) {
        int x = cur[tid] + ((tid >= off) ? cur[tid - off] : 0);
        nxt[tid] = x;
        __syncthreads();
        int* t = cur; cur = nxt; nxt = t;
    }
    if (tid < n) data[tid] = cur[tid] - v;   // exclusive
}

__global__ void scan_final(const int* __restrict__ hist, const int* __restrict__ blockOffs,
                           int* __restrict__ offs, int n) {
    __shared__ int a[256], b2[256];
    int tid = threadIdx.x;
    int i = blockIdx.x * 256 + tid;
    int v = (i < n) ? hist[i] : 0;
    a[tid] = v;
    __syncthreads();
    int* cur = a; int* nxt = b2;
    for (int off = 1; off < 256; off <<= 1) {
        int x = cur[tid] + ((tid >= off) ? cur[tid - off] : 0);
        nxt[tid] = x;
        __syncthreads();
        int* t = cur; cur = nxt; nxt = t;
    }
    if (i < n) offs[i] = cur[tid] - v + blockOffs[blockIdx.x];
}

// ---------------- scatter: int4 payloads {idx, idx, eb} + fast exp ----------------
__global__ __launch_bounds__(256) void scatter_both(const int* __restrict__ src,
                                                    const int* __restrict__ dst,
                                                    const int* __restrict__ rel,
                                                    int* __restrict__ offsSrc,
                                                    const int* __restrict__ blockOffs,
                                                    const float* __restrict__ qs,
                                                    const float* __restrict__ qd,
                                                    const float* __restrict__ qr,
                                                    const float* __restrict__ a2b,
                                                    int4* __restrict__ drE,
                                                    int4* __restrict__ sdE) {
    __shared__ int lh[512];
    int tid = threadIdx.x;
    lh[tid] = 0; lh[tid + 256] = 0;
    __syncthreads();
    float bb = a2b[0];
    int base = blockIdx.x * EPB;
    const int* bo = &blockOffs[blockIdx.x * 512];
#pragma unroll
    for (int j = 0; j < 4; ++j) {
        int e = base + j * 256 + tid;
        if (e < NEDGE_C) {
            int s = src[e], d = dst[e], r = rel[e];
            float b = qs[s] + qd[d] + qr[r] + bb;
            b = (b > 0.f) ? b : 0.01f * b;
            float eb = __expf(b);
            int ebi = __float_as_int(eb);
            int p = atomicAdd(&offsSrc[s], 1);
            drE[p] = make_int4(d, r, ebi, 0);
            int lr = atomicAdd(&lh[r], 1);
            sdE[bo[r] + lr] = make_int4(s, d, ebi, 0);
        }
    }
}

// ---------------- rel phase: 8 partial blocks per relation, pk unpack -----------------
__global__ __launch_bounds__(256) void rel_phase(const unsigned short* __restrict__ PsH,
                                                 const unsigned short* __restrict__ PdH,
                                                 const int* __restrict__ relStart,
                                                 const int4* __restrict__ sdE,
                                                 float* __restrict__ relpart) {
    int r = blockIdx.x >> 3;
    int p = blockIdx.x & 7;
    int start = relStart[r];
    int end = relStart[r + 1];
    int tid = threadIdx.x;
    int w = tid >> 6;
    int h = (tid >> 5) & 1;
    int l = tid & 31;
    int slot = p * 8 + w * 2 + h;
    f32x2 acc0 = {0.f, 0.f}, acc1 = {0.f, 0.f};
    float ebs = 0.f;
    for (int i = start + slot; i < end; i += 64) {
        int4 sd = sdE[i];
        int s = sd.x, d = sd.y;
        float eb = __int_as_float(sd.z);
        uint2 pw = *(const uint2*)&PsH[(size_t)s * 128 + l * 4];
        uint2 dw = *(const uint2*)&PdH[(size_t)d * 128 + l * 4];
        f32x2 ebp = {eb, eb};
        acc0 = ebp * (bfpair(pw.x) + bfpair(dw.x)) + acc0;
        acc1 = ebp * (bfpair(pw.y) + bfpair(dw.y)) + acc1;
        ebs += eb;
    }
    __shared__ float vred[8][128];
    __shared__ float sred[8];
    int sub = w * 2 + h;
    float4 accv = make_float4(acc0.x, acc0.y, acc1.x, acc1.y);
    *(float4*)&vred[sub][l * 4] = accv;
    if (l == 0) sred[sub] = ebs;
    __syncthreads();
    if (tid < 128) {
        float v = 0.f;
#pragma unroll
        for (int k2 = 0; k2 < 8; ++k2) v += vred[k2][tid];
        float e = 0.f;
#pragma unroll
        for (int k2 = 0; k2 < 8; ++k2) e += sred[k2];
        int pi = r * 8 + p;
        relpart[pi * 132 + tid] = v;
        if (tid == 0) relpart[pi * 132 + 128] = e;
    }
}

__global__ void rel_fin(const float* __restrict__ relpart, const float* __restrict__ Pr,
                        const int* __restrict__ relStart, float* __restrict__ outRel) {
    int r = blockIdx.x;
    int o = threadIdx.x;
    float v = 0.f, e = 0.f;
#pragma unroll
    for (int p = 0; p < 8; ++p) {
        v += relpart[(r * 8 + p) * 132 + o];
        e += relpart[(r * 8 + p) * 132 + 128];
    }
    float cnt = (float)(relStart[r + 1] - relStart[r]);
    float h = (v + e * Pr[r * 128 + o]) / fmaxf(cnt, 1.f);
    outRel[r * 128 + o] = (h > 0.f) ? h : (__expf(h) - 1.f);
}

// ---------------- src phase: 4 edges in flight, int4 record, pk unpack, fast exp ------
__global__ __launch_bounds__(256) void src_phase(const unsigned short* __restrict__ PsH,
                                                 const unsigned short* __restrict__ PdH,
                                                 const unsigned short* __restrict__ PrH,
                                                 const int* __restrict__ offsSrc,
                                                 const int4* __restrict__ drE,
                                                 float* __restrict__ out) {
    int wid = (blockIdx.x * 256 + threadIdx.x) >> 6;
    if (wid >= N_ENT_C) return;
    int lane = threadIdx.x & 63;
    int g = lane >> 4, l = lane & 15;   // 4 groups x 16 lanes; lane covers cols l*8..l*8+7
    int s = wid;
    int start = (s == 0) ? 0 : offsSrc[s - 1];
    int end = offsSrc[s];
    float* dstp = &out[(size_t)s * 128];
    if (end == start) {
        if (g == 0) {
            *(float4*)&dstp[l * 8] = make_float4(0.f, 0.f, 0.f, 0.f);
            *(float4*)&dstp[l * 8 + 4] = make_float4(0.f, 0.f, 0.f, 0.f);
        }
        return;
    }
    f32x2 accp[4];
#pragma unroll
    for (int j = 0; j < 4; ++j) accp[j] = (f32x2){0.f, 0.f};
    float ebs = 0.f;
    for (int i = start + g; i < end; i += 4) {
        int4 er = drE[i];
        int d = er.x, r = er.y;
        float eb = __int_as_float(er.z);
        uint4 dw = *(const uint4*)&PdH[(size_t)d * 128 + l * 8];
        uint4 rw = *(const uint4*)&PrH[(size_t)r * 128 + l * 8];
        f32x2 ebp = {eb, eb};
        accp[0] = ebp * (bfpair(dw.x) + bfpair(rw.x)) + accp[0];
        accp[1] = ebp * (bfpair(dw.y) + bfpair(rw.y)) + accp[1];
        accp[2] = ebp * (bfpair(dw.z) + bfpair(rw.z)) + accp[2];
        accp[3] = ebp * (bfpair(dw.w) + bfpair(rw.w)) + accp[3];
        ebs += eb;
    }
    float a8[8] = {accp[0].x, accp[0].y, accp[1].x, accp[1].y,
                   accp[2].x, accp[2].y, accp[3].x, accp[3].y};
#pragma unroll
    for (int j = 0; j < 8; ++j) {
        a8[j] += __shfl_xor(a8[j], 16);
        a8[j] += __shfl_xor(a8[j], 32);
    }
    ebs += __shfl_xor(ebs, 16);
    ebs += __shfl_xor(ebs, 32);
    if (g == 0) {
        float inv = 1.f / ebs;
        u16x8 ps = *(const u16x8*)&PsH[(size_t)s * 128 + l * 8];
        float h[8];
#pragma unroll
        for (int j = 0; j < 8; ++j) {
            float x = bf2f(ps[j]) + a8[j] * inv;
            h[j] = (x > 0.f) ? x : (__expf(x) - 1.f);
        }
        *(float4*)&dstp[l * 8]     = make_float4(h[0], h[1], h[2], h[3]);
        *(float4*)&dstp[l * 8 + 4] = make_float4(h[4], h[5], h[6], h[7]);
    }
}

extern "C" void kernel_launch(void* const* d_in, const int* in_sizes, int n_in,
                              void* d_out, int out_size, void* d_ws, size_t ws_size,
                              hipStream_t stream) {
    const float* ent  = (const float*)d_in[0];
    const float* rele = (const float*)d_in[1];
    const float* aw   = (const float*)d_in[2];
    const float* ab   = (const float*)d_in[3];
    const float* a2w  = (const float*)d_in[4];
    const float* a2b  = (const float*)d_in[5];
    const int* src    = (const int*)d_in[6];
    const int* dst    = (const int*)d_in[7];
    const int* rel    = (const int*)d_in[8];
    float* out = (float*)d_out;

    float* ws = (float*)d_ws;
    unsigned short* Wthi = (unsigned short*)(ws + OFF_WTHI);
    unsigned short* Wtlo = (unsigned short*)(ws + OFF_WTLO);
    float* Wtr = ws + OFF_WTR;
    float* Pr  = ws + OFF_PR;
    unsigned short* PrH = (unsigned short*)(ws + OFF_PRH);
    float* qr  = ws + OFF_QR;
    float* qs  = ws + OFF_QS;
    float* qd  = ws + OFF_QD;
    int* offsSrc = (int*)(ws + OFF_OSRC);
    int4* drE    = (int4*)(ws + OFF_DRE);
    unsigned short* PsH = (unsigned short*)(ws + OFF_PSH);
    unsigned short* PdH = (unsigned short*)(ws + OFF_PDH);

    int* dI = (int*)d_out;
    int* histSrc  = dI + DO_HSRC;
    int* bsum     = dI + DO_BSUM;
    int* relStart = dI + DO_RELSTART;
    int* part8    = dI + DO_PART8;
    int* chunkOff = dI + DO_CHUNKOFF;
    int* blkHist  = dI + DO_BLKHIST;
    int* blockOffs= dI + DO_BLKOFFS;
    int4* sdE     = (int4*)(dI + DO_SDE);
    float* relpart = (float*)dI + DO_RELP;

    hipMemsetAsync(ws + OFF_QR, 0, (size_t)(OFF_OSRC - OFF_QR) * sizeof(float), stream);

    prep_w<<<192, 256, 0, stream>>>(aw, Wthi, Wtlo, Wtr);
    rel_proj<<<N_REL_C, 128, 0, stream>>>(rele, Wtr, ab, a2w, Pr, PrH, qr);
    ent_mfma5<<<MFMA4_GRID, 512, 0, stream>>>(ent, Wthi, Wtlo, a2w, PsH, PdH, qs, qd);

    // d_out entity region used purely as sort scratch now
    hipMemsetAsync(histSrc, 0, (size_t)N_ENT_C * sizeof(int), stream);
    edge_hist<<<NB_EDGE, 256, 0, stream>>>(src, rel, histSrc, blkHist);
    colsum<<<8, 512, 0, stream>>>(blkHist, part8);
    scan512<<<1, 512, 0, stream>>>(part8, relStart, chunkOff);
    colscan<<<8, 512, 0, stream>>>(blkHist, chunkOff, blockOffs);
    scan_blockred<<<SCAN_BLOCKS, 256, 0, stream>>>(histSrc, bsum, N_ENT_C);
    scan_single<<<1, 1024, 0, stream>>>(bsum, SCAN_BLOCKS);
    scan_final<<<SCAN_BLOCKS, 256, 0, stream>>>(histSrc, bsum, offsSrc, N_ENT_C);
    scatter_both<<<NB_EDGE, 256, 0, stream>>>(src, dst, rel, offsSrc, blockOffs,
                                              qs, qd, qr, a2b, drE, sdE);

    rel_phase<<<N_REL_C * 8, 256, 0, stream>>>(PsH, PdH, relStart, sdE, relpart);
    rel_fin<<<N_REL_C, 128, 0, stream>>>(relpart, Pr, relStart, out + (size_t)N_ENT_C * 128);

    src_phase<<<(N_ENT_C + 3) / 4, 256, 0, stream>>>(PsH, PdH, PrH, offsSrc, drE, out);
}

// Round 18
// 243.552 us; speedup vs baseline: 1.0019x; 1.0003x over previous
//
#include <hip/hip_runtime.h>
#include <hip/hip_bf16.h>

#define N_ENT_C 100000
#define N_REL_C 500
#define NEDGE_C 500000
#define SCAN_BLOCKS 391   // ceil(100000/256)
#define EPB 1024          // edges per block for rel sort
#define NB_EDGE 489       // ceil(500000/1024)
#define CHUNK_B 62        // ceil(489/8)
#define MT_TOTAL 6250     // 100000/16 m-tiles, exact
#define MFMA4_GRID 512    // grid-stride m-loop
#define CVT_GRID 1563     // (unused; kept for reference)

// ---------------- ws layout (float offsets) — 15.25M < proven 25.7M -------------------
#define OFF_WTHI  0         // Wt hi bf16 [256][128] -> 16384 f32 slots
#define OFF_WTLO  16384
#define OFF_WTR   32768     // Wtr f32 [128][128]
#define OFF_PR    49152     // Pr f32 [500][128]
#define OFF_PRH   113152    // PrH bf16 [500][128]
#define OFF_QR    145920    // qr f32 [512]
#define OFF_QS    146432    // qs f32 [100000]   (atomic accum, zeroed)
#define OFF_QD    246432    // qd f32 [100000]   (atomic accum, zeroed)
#define OFF_OSRC  346432    // offsSrc [100000]
#define OFF_DRE   446432    // drE int4 [500000] {d,r,eb,-} = 2M ints (16B-aligned)
#define OFF_PSH   2446432   // PsH bf16 [100000][128]
#define OFF_PDH   8846432   // PdH bf16 [100000][128]
// end = 15,246,432 floats = 61 MB

// ---------------- d_out entity region (12.8M f32) as time-shared scratch --------------
#define DO_HSRC     0         // histSrc [100000]
#define DO_BSUM     100000    // blockSums [512]
#define DO_RELSTART 100512    // relStart [512]
#define DO_PART8    101024    // partial [8][512]
#define DO_CHUNKOFF 105120    // chunkOff [8][512]
#define DO_BLKHIST  109216    // blkHist [489][512]
#define DO_BLKOFFS  359584    // blockOffs [489][512]
#define DO_SDE      609952    // sdE int4 [500000] {s,d,eb,-} (16B-aligned)
#define DO_RELP     2609952   // relpart [4000][132] -> end 3,137,952 < 12.8M

typedef short bf16x8 __attribute__((ext_vector_type(8)));   // 8 bf16 = 16B = 4 VGPRs
typedef float f32x4  __attribute__((ext_vector_type(4)));
typedef float f32x2  __attribute__((ext_vector_type(2)));
typedef unsigned short u16x8 __attribute__((ext_vector_type(8)));

__device__ inline unsigned short bf_rne(float x) {
    unsigned int u = __float_as_uint(x);
    u += 0x7FFF + ((u >> 16) & 1);          // round-nearest-even
    return (unsigned short)(u >> 16);
}
__device__ inline float bf2f(unsigned short h) {
    return __uint_as_float(((unsigned int)h) << 16);
}
__device__ inline f32x2 bfpair(unsigned int w) {
    f32x2 r;
    r.x = __uint_as_float(w << 16);
    r.y = __uint_as_float(w & 0xFFFF0000u);
    return r;
}

// ---------------- weight prep ----------------
__global__ void prep_w(const float* __restrict__ aw, unsigned short* __restrict__ Wthi,
                       unsigned short* __restrict__ Wtlo, float* __restrict__ Wtr) {
    int idx = blockIdx.x * 256 + threadIdx.x;   // 0..49151
    if (idx < 32768) {
        int n = idx >> 7, k = idx & 127;
        float v = (n < 128) ? aw[n * 384 + k] : aw[(n - 128) * 384 + 128 + k];
        unsigned short h = bf_rne(v);
        Wthi[idx] = h;
        Wtlo[idx] = bf_rne(v - bf2f(h));
    } else if (idx < 49152) {
        int t = idx - 32768;
        int k = t >> 7, o = t & 127;
        Wtr[t] = aw[o * 384 + 256 + k];
    }
}

// ---------------- rel projection + qr epilogue ----------------
__global__ void rel_proj(const float* __restrict__ rele, const float* __restrict__ Wtr,
                         const float* __restrict__ ab, const float* __restrict__ a2w,
                         float* __restrict__ Pr, unsigned short* __restrict__ PrH,
                         float* __restrict__ qr) {
    int r = blockIdx.x;
    int o = threadIdx.x;
    float acc = ab[o];
    for (int k = 0; k < 128; ++k)
        acc = fmaf(rele[r * 128 + k], Wtr[k * 128 + o], acc);
    Pr[r * 128 + o] = acc;
    PrH[r * 128 + o] = bf_rne(acc);
    __shared__ float red[128];
    red[o] = acc * a2w[o];
    __syncthreads();
    for (int off = 64; off > 0; off >>= 1) {
        if (o < off) red[o] += red[o + off];
        __syncthreads();
    }
    if (o == 0) qr[r] = red[0];
}

// ---------------- ent projection: W in LDS, fused f32->bf16 hi/lo conversion ----------
// D = W · ent^T. 8 waves x 32 n-cols; W hi/lo in 128 KB LDS (16B slots XOR-swizzled).
// Each wave reads ent rows directly (f32), converts in regs (bit-identical to ent_cvt).
__global__ __launch_bounds__(512, 2) void ent_mfma5(const float* __restrict__ ent,
                                                    const unsigned short* __restrict__ Wthi,
                                                    const unsigned short* __restrict__ Wtlo,
                                                    const float* __restrict__ a2w,
                                                    unsigned short* __restrict__ PsH,
                                                    unsigned short* __restrict__ PdH,
                                                    float* __restrict__ qs,
                                                    float* __restrict__ qd) {
    __shared__ __align__(16) char shw[131072];   // Whi [0,64K), Wlo [64K,128K)
    const int tid = threadIdx.x;

    // stage W (once per block): 8192 16B-chunks, swizzled
#pragma unroll
    for (int it = 0; it < 16; ++it) {
        int g = it * 512 + tid;          // 0..8191
        int arr = g >> 12;               // 0 = hi, 1 = lo
        int gg = g & 4095;
        int n = gg >> 4, slot = gg & 15;
        const unsigned short* srcp = (arr ? Wtlo : Wthi) + n * 128 + slot * 8;
        uint4 v = *(const uint4*)srcp;
        *(uint4*)(shw + arr * 65536 + n * 256 + ((slot ^ (n & 7)) << 4)) = v;
    }
    __syncthreads();

    const int w = tid >> 6, lane = tid & 63;
    const int l15 = lane & 15, lh = lane >> 4;
    const int n0 = w * 32;

    float a2v[2][4];
#pragma unroll
    for (int nf = 0; nf < 2; ++nf)
#pragma unroll
        for (int v = 0; v < 4; ++v)
            a2v[nf][v] = a2w[(n0 + nf * 16 + lh * 4 + v) & 127];

    const bool isPs = (w < 4);
    unsigned short* PH = isPs ? PsH : PdH;
    float* qout = isPs ? qs : qd;
    const int colbase = (n0 & 127) + lh * 4;

    // per-lane LDS offsets for this wave's two n-rows
    int nA = n0 + l15, nB = n0 + 16 + l15;
    int offA = nA * 256, offB = nB * 256;
    int swzA = (nA & 7), swzB = (nB & 7);

    f32x4 zz = {0.f, 0.f, 0.f, 0.f};

    for (int mt = blockIdx.x; mt < MT_TOTAL; mt += MFMA4_GRID) {
        const int m = mt * 16 + l15;
        const float* rp = ent + (size_t)m * 128;
        // issue all 8 ent loads up front (one latency per tile)
        float4 e0[4], e1[4];
#pragma unroll
        for (int ks = 0; ks < 4; ++ks) {
            int kb = ks * 32 + lh * 8;
            e0[ks] = *(const float4*)(rp + kb);
            e1[ks] = *(const float4*)(rp + kb + 4);
        }

        f32x4 acc[2];
        acc[0] = zz; acc[1] = zz;
#pragma unroll
        for (int ks = 0; ks < 4; ++ks) {
            float f[8] = {e0[ks].x, e0[ks].y, e0[ks].z, e0[ks].w,
                          e1[ks].x, e1[ks].y, e1[ks].z, e1[ks].w};
            bf16x8 eh, el;
#pragma unroll
            for (int j = 0; j < 8; ++j) {
                unsigned short h = bf_rne(f[j]);
                eh[j] = (short)h;
                el[j] = (short)bf_rne(f[j] - bf2f(h));
            }
            int slot = ks * 4 + lh;
            int oA = offA + ((slot ^ swzA) << 4);
            int oB = offB + ((slot ^ swzB) << 4);
            bf16x8 whA = *(const bf16x8*)(shw + oA);
            bf16x8 wlA = *(const bf16x8*)(shw + 65536 + oA);
            bf16x8 whB = *(const bf16x8*)(shw + oB);
            bf16x8 wlB = *(const bf16x8*)(shw + 65536 + oB);
            acc[0] = __builtin_amdgcn_mfma_f32_16x16x32_bf16(whA, eh, acc[0], 0, 0, 0);
            acc[0] = __builtin_amdgcn_mfma_f32_16x16x32_bf16(whA, el, acc[0], 0, 0, 0);
            acc[0] = __builtin_amdgcn_mfma_f32_16x16x32_bf16(wlA, eh, acc[0], 0, 0, 0);
            acc[1] = __builtin_amdgcn_mfma_f32_16x16x32_bf16(whB, eh, acc[1], 0, 0, 0);
            acc[1] = __builtin_amdgcn_mfma_f32_16x16x32_bf16(whB, el, acc[1], 0, 0, 0);
            acc[1] = __builtin_amdgcn_mfma_f32_16x16x32_bf16(wlB, eh, acc[1], 0, 0, 0);
        }

        float qp = 0.f;
#pragma unroll
        for (int nf = 0; nf < 2; ++nf) {
            ushort4 st;
            st.x = bf_rne(acc[nf][0]);
            st.y = bf_rne(acc[nf][1]);
            st.z = bf_rne(acc[nf][2]);
            st.w = bf_rne(acc[nf][3]);
#pragma unroll
            for (int v = 0; v < 4; ++v) qp = fmaf(acc[nf][v], a2v[nf][v], qp);
            *(ushort4*)&PH[(size_t)m * 128 + colbase + nf * 16] = st;
        }
        qp += __shfl_xor(qp, 16);
        qp += __shfl_xor(qp, 32);
        if (lane < 16) unsafeAtomicAdd(&qout[m], qp);
    }
}

// ---------------- rel-key block histogram (LDS) + src global hist ----------------
__global__ __launch_bounds__(256) void edge_hist(const int* __restrict__ src,
                                                 const int* __restrict__ rel,
                                                 int* __restrict__ histSrc,
                                                 int* __restrict__ blkHist) {
    __shared__ int lh[512];
    int tid = threadIdx.x;
    lh[tid] = 0; lh[tid + 256] = 0;
    __syncthreads();
    int base = blockIdx.x * EPB;
#pragma unroll
    for (int j = 0; j < 4; ++j) {
        int e = base + j * 256 + tid;
        if (e < NEDGE_C) {
            atomicAdd(&histSrc[src[e]], 1);
            atomicAdd(&lh[rel[e]], 1);
        }
    }
    __syncthreads();
    blkHist[blockIdx.x * 512 + tid] = lh[tid];
    blkHist[blockIdx.x * 512 + 256 + tid] = lh[tid + 256];
}

__global__ void colsum(const int* __restrict__ blkHist, int* __restrict__ partial) {
    int r = threadIdx.x;
    int k = blockIdx.x;
    int b0 = k * CHUNK_B;
    int b1 = min(b0 + CHUNK_B, NB_EDGE);
    int t = 0;
    for (int b = b0; b < b1; ++b) t += blkHist[b * 512 + r];
    partial[k * 512 + r] = t;
}

__global__ void scan512(const int* __restrict__ partial, int* __restrict__ relStart,
                        int* __restrict__ chunkOff) {
    __shared__ int a[512], b2[512];
    int tid = threadIdx.x;
    int p8[8];
    int t = 0;
#pragma unroll
    for (int k = 0; k < 8; ++k) { p8[k] = partial[k * 512 + tid]; t += p8[k]; }
    a[tid] = t;
    __syncthreads();
    int v = t;
    int* cur = a; int* nxt = b2;
    for (int off = 1; off < 512; off <<= 1) {
        int x = cur[tid] + ((tid >= off) ? cur[tid - off] : 0);
        nxt[tid] = x;
        __syncthreads();
        int* tmp = cur; cur = nxt; nxt = tmp;
    }
    int excl = cur[tid] - v;
    relStart[tid] = excl;
    int run = excl;
#pragma unroll
    for (int k = 0; k < 8; ++k) { chunkOff[k * 512 + tid] = run; run += p8[k]; }
}

__global__ void colscan(const int* __restrict__ blkHist, const int* __restrict__ chunkOff,
                        int* __restrict__ blockOffs) {
    int r = threadIdx.x;
    int k = blockIdx.x;
    int b0 = k * CHUNK_B;
    int b1 = min(b0 + CHUNK_B, NB_EDGE);
    int off = chunkOff[k * 512 + r];
    for (int b = b0; b < b1; ++b) {
        blockOffs[b * 512 + r] = off;
        off += blkHist[b * 512 + r];
    }
}

__global__ void scan_blockred(const int* __restrict__ hist, int* __restrict__ blockSums, int n) {
    __shared__ int s[256];
    int tid = threadIdx.x;
    int i = blockIdx.x * 256 + tid;
    s[tid] = (i < n) ? hist[i] : 0;
    __syncthreads();
    for (int off = 128; off > 0; off >>= 1) {
        if (tid < off) s[tid] += s[tid + off];
        __syncthreads();
    }
    if (tid == 0) blockSums[blockIdx.x] = s[0];
}

__global__ void scan_single(int* __restrict__ data, int n) {
    __shared__ int a[1024], b2[1024];
    int tid = threadIdx.x;
    int v = (tid < n) ? data[tid] : 0;
    a[tid] = v;
    __syncthreads();
    int* cur = a; int* nxt = b2;
    for (int off = 1; off < 1024; off <<= 1) {
        int x = cur[tid] + ((tid >= off) ? cur[tid - off] : 0);
        nxt[tid] = x;
        __syncthreads();
        int* t = cur; cur = nxt; nxt = t;
    }
    if (tid < n) data[tid] = cur[tid] - v;   // exclusive
}

__global__ void scan_final(const int* __restrict__ hist, const int* __restrict__ blockOffs,
                           int* __restrict__ offs, int n) {
    __shared__ int a[256], b2[256];
    int tid = threadIdx.x;
    int i = blockIdx.x * 256 + tid;
    int v = (i < n) ? hist[i] : 0;
    a[tid] = v;
    __syncthreads();
    int* cur = a; int* nxt = b2;
    for (int off = 1; off < 256; off <<= 1) {
        int x = cur[tid] + ((tid >= off) ? cur[tid - off] : 0);
        nxt[tid] = x;
        __syncthreads();
        int* t = cur; cur = nxt; nxt = t;
    }
    if (i < n) offs[i] = cur[tid] - v + blockOffs[blockIdx.x];
}

// ---------------- scatter: int4 payloads {idx, idx, eb} + fast exp ----------------
__global__ __launch_bounds__(256) void scatter_both(const int* __restrict__ src,
                                                    const int* __restrict__ dst,
                                                    const int* __restrict__ rel,
                                                    int* __restrict__ offsSrc,
                                                    const int* __restrict__ blockOffs,
                                                    const float* __restrict__ qs,
                                                    const float* __restrict__ qd,
                                                    const float* __restrict__ qr,
                                                    const float* __restrict__ a2b,
                                                    int4* __restrict__ drE,
                                                    int4* __restrict__ sdE) {
    __shared__ int lh[512];
    int tid = threadIdx.x;
    lh[tid] = 0; lh[tid + 256] = 0;
    __syncthreads();
    float bb = a2b[0];
    int base = blockIdx.x * EPB;
    const int* bo = &blockOffs[blockIdx.x * 512];
#pragma unroll
    for (int j = 0; j < 4; ++j) {
        int e = base + j * 256 + tid;
        if (e < NEDGE_C) {
            int s = src[e], d = dst[e], r = rel[e];
            float b = qs[s] + qd[d] + qr[r] + bb;
            b = (b > 0.f) ? b : 0.01f * b;
            float eb = __expf(b);
            int ebi = __float_as_int(eb);
            int p = atomicAdd(&offsSrc[s], 1);
            drE[p] = make_int4(d, r, ebi, 0);
            int lr = atomicAdd(&lh[r], 1);
            sdE[bo[r] + lr] = make_int4(s, d, ebi, 0);
        }
    }
}

// ---------------- rel phase: 8 partial blocks per relation, pk unpack -----------------
__global__ __launch_bounds__(256) void rel_phase(const unsigned short* __restrict__ PsH,
                                                 const unsigned short* __restrict__ PdH,
                                                 const int* __restrict__ relStart,
                                                 const int4* __restrict__ sdE,
                                                 float* __restrict__ relpart) {
    int r = blockIdx.x >> 3;
    int p = blockIdx.x & 7;
    int start = relStart[r];
    int end = relStart[r + 1];
    int tid = threadIdx.x;
    int w = tid >> 6;
    int h = (tid >> 5) & 1;
    int l = tid & 31;
    int slot = p * 8 + w * 2 + h;
    f32x2 acc0 = {0.f, 0.f}, acc1 = {0.f, 0.f};
    float ebs = 0.f;
    for (int i = start + slot; i < end; i += 64) {
        int4 sd = sdE[i];
        int s = sd.x, d = sd.y;
        float eb = __int_as_float(sd.z);
        uint2 pw = *(const uint2*)&PsH[(size_t)s * 128 + l * 4];
        uint2 dw = *(const uint2*)&PdH[(size_t)d * 128 + l * 4];
        f32x2 ebp = {eb, eb};
        acc0 = ebp * (bfpair(pw.x) + bfpair(dw.x)) + acc0;
        acc1 = ebp * (bfpair(pw.y) + bfpair(dw.y)) + acc1;
        ebs += eb;
    }
    __shared__ float vred[8][128];
    __shared__ float sred[8];
    int sub = w * 2 + h;
    float4 accv = make_float4(acc0.x, acc0.y, acc1.x, acc1.y);
    *(float4*)&vred[sub][l * 4] = accv;
    if (l == 0) sred[sub] = ebs;
    __syncthreads();
    if (tid < 128) {
        float v = 0.f;
#pragma unroll
        for (int k2 = 0; k2 < 8; ++k2) v += vred[k2][tid];
        float e = 0.f;
#pragma unroll
        for (int k2 = 0; k2 < 8; ++k2) e += sred[k2];
        int pi = r * 8 + p;
        relpart[pi * 132 + tid] = v;
        if (tid == 0) relpart[pi * 132 + 128] = e;
    }
}

__global__ void rel_fin(const float* __restrict__ relpart, const float* __restrict__ Pr,
                        const int* __restrict__ relStart, float* __restrict__ outRel) {
    int r = blockIdx.x;
    int o = threadIdx.x;
    float v = 0.f, e = 0.f;
#pragma unroll
    for (int p = 0; p < 8; ++p) {
        v += relpart[(r * 8 + p) * 132 + o];
        e += relpart[(r * 8 + p) * 132 + 128];
    }
    float cnt = (float)(relStart[r + 1] - relStart[r]);
    float h = (v + e * Pr[r * 128 + o]) / fmaxf(cnt, 1.f);
    outRel[r * 128 + o] = (h > 0.f) ? h : (__expf(h) - 1.f);
}

// ---------------- src phase: 4 edges in flight, int4 record, pk unpack, fast exp ------
__global__ __launch_bounds__(256) void src_phase(const unsigned short* __restrict__ PsH,
                                                 const unsigned short* __restrict__ PdH,
                                                 const unsigned short* __restrict__ PrH,
                                                 const int* __restrict__ offsSrc,
                                                 const int4* __restrict__ drE,
                                                 float* __restrict__ out) {
    int wid = (blockIdx.x * 256 + threadIdx.x) >> 6;
    if (wid >= N_ENT_C) return;
    int lane = threadIdx.x & 63;
    int g = lane >> 4, l = lane & 15;   // 4 groups x 16 lanes; lane covers cols l*8..l*8+7
    int s = wid;
    int start = (s == 0) ? 0 : offsSrc[s - 1];
    int end = offsSrc[s];
    float* dstp = &out[(size_t)s * 128];
    if (end == start) {
        if (g == 0) {
            *(float4*)&dstp[l * 8] = make_float4(0.f, 0.f, 0.f, 0.f);
            *(float4*)&dstp[l * 8 + 4] = make_float4(0.f, 0.f, 0.f, 0.f);
        }
        return;
    }
    f32x2 accp[4];
#pragma unroll
    for (int j = 0; j < 4; ++j) accp[j] = (f32x2){0.f, 0.f};
    float ebs = 0.f;
    for (int i = start + g; i < end; i += 4) {
        int4 er = drE[i];
        int d = er.x, r = er.y;
        float eb = __int_as_float(er.z);
        uint4 dw = *(const uint4*)&PdH[(size_t)d * 128 + l * 8];
        uint4 rw = *(const uint4*)&PrH[(size_t)r * 128 + l * 8];
        f32x2 ebp = {eb, eb};
        accp[0] = ebp * (bfpair(dw.x) + bfpair(rw.x)) + accp[0];
        accp[1] = ebp * (bfpair(dw.y) + bfpair(rw.y)) + accp[1];
        accp[2] = ebp * (bfpair(dw.z) + bfpair(rw.z)) + accp[2];
        accp[3] = ebp * (bfpair(dw.w) + bfpair(rw.w)) + accp[3];
        ebs += eb;
    }
    float a8[8] = {accp[0].x, accp[0].y, accp[1].x, accp[1].y,
                   accp[2].x, accp[2].y, accp[3].x, accp[3].y};
#pragma unroll
    for (int j = 0; j < 8; ++j) {
        a8[j] += __shfl_xor(a8[j], 16);
        a8[j] += __shfl_xor(a8[j], 32);
    }
    ebs += __shfl_xor(ebs, 16);
    ebs += __shfl_xor(ebs, 32);
    if (g == 0) {
        float inv = 1.f / ebs;
        u16x8 ps = *(const u16x8*)&PsH[(size_t)s * 128 + l * 8];
        float h[8];
#pragma unroll
        for (int j = 0; j < 8; ++j) {
            float x = bf2f(ps[j]) + a8[j] * inv;
            h[j] = (x > 0.f) ? x : (__expf(x) - 1.f);
        }
        *(float4*)&dstp[l * 8]     = make_float4(h[0], h[1], h[2], h[3]);
        *(float4*)&dstp[l * 8 + 4] = make_float4(h[4], h[5], h[6], h[7]);
    }
}

extern "C" void kernel_launch(void* const* d_in, const int* in_sizes, int n_in,
                              void* d_out, int out_size, void* d_ws, size_t ws_size,
                              hipStream_t stream) {
    const float* ent  = (const float*)d_in[0];
    const float* rele = (const float*)d_in[1];
    const float* aw   = (const float*)d_in[2];
    const float* ab   = (const float*)d_in[3];
    const float* a2w  = (const float*)d_in[4];
    const float* a2b  = (const float*)d_in[5];
    const int* src    = (const int*)d_in[6];
    const int* dst    = (const int*)d_in[7];
    const int* rel    = (const int*)d_in[8];
    float* out = (float*)d_out;

    float* ws = (float*)d_ws;
    unsigned short* Wthi = (unsigned short*)(ws + OFF_WTHI);
    unsigned short* Wtlo = (unsigned short*)(ws + OFF_WTLO);
    float* Wtr = ws + OFF_WTR;
    float* Pr  = ws + OFF_PR;
    unsigned short* PrH = (unsigned short*)(ws + OFF_PRH);
    float* qr  = ws + OFF_QR;
    float* qs  = ws + OFF_QS;
    float* qd  = ws + OFF_QD;
    int* offsSrc = (int*)(ws + OFF_OSRC);
    int4* drE    = (int4*)(ws + OFF_DRE);
    unsigned short* PsH = (unsigned short*)(ws + OFF_PSH);
    unsigned short* PdH = (unsigned short*)(ws + OFF_PDH);

    int* dI = (int*)d_out;
    int* histSrc  = dI + DO_HSRC;
    int* bsum     = dI + DO_BSUM;
    int* relStart = dI + DO_RELSTART;
    int* part8    = dI + DO_PART8;
    int* chunkOff = dI + DO_CHUNKOFF;
    int* blkHist  = dI + DO_BLKHIST;
    int* blockOffs= dI + DO_BLKOFFS;
    int4* sdE     = (int4*)(dI + DO_SDE);
    float* relpart = (float*)dI + DO_RELP;

    hipMemsetAsync(ws + OFF_QR, 0, (size_t)(OFF_OSRC - OFF_QR) * sizeof(float), stream);

    prep_w<<<192, 256, 0, stream>>>(aw, Wthi, Wtlo, Wtr);
    rel_proj<<<N_REL_C, 128, 0, stream>>>(rele, Wtr, ab, a2w, Pr, PrH, qr);
    ent_mfma5<<<MFMA4_GRID, 512, 0, stream>>>(ent, Wthi, Wtlo, a2w, PsH, PdH, qs, qd);

    // d_out entity region used purely as sort scratch now
    hipMemsetAsync(histSrc, 0, (size_t)N_ENT_C * sizeof(int), stream);
    edge_hist<<<NB_EDGE, 256, 0, stream>>>(src, rel, histSrc, blkHist);
    colsum<<<8, 512, 0, stream>>>(blkHist, part8);
    scan512<<<1, 512, 0, stream>>>(part8, relStart, chunkOff);
    colscan<<<8, 512, 0, stream>>>(blkHist, chunkOff, blockOffs);
    scan_blockred<<<SCAN_BLOCKS, 256, 0, stream>>>(histSrc, bsum, N_ENT_C);
    scan_single<<<1, 1024, 0, stream>>>(bsum, SCAN_BLOCKS);
    scan_final<<<SCAN_BLOCKS, 256, 0, stream>>>(histSrc, bsum, offsSrc, N_ENT_C);
    scatter_both<<<NB_EDGE, 256, 0, stream>>>(src, dst, rel, offsSrc, blockOffs,
                                              qs, qd, qr, a2b, drE, sdE);

    rel_phase<<<N_REL_C * 8, 256, 0, stream>>>(PsH, PdH, relStart, sdE, relpart);
    rel_fin<<<N_REL_C, 128, 0, stream>>>(relpart, Pr, relStart, out + (size_t)N_ENT_C * 128);

    src_phase<<<(N_ENT_C + 3) / 4, 256, 0, stream>>>(PsH, PdH, PrH, offsSrc, drE, out);
}

// Round 19
// 238.619 us; speedup vs baseline: 1.0226x; 1.0207x over previous
//
#include <hip/hip_runtime.h>
#include <hip/hip_bf16.h>

#define N_ENT_C 100000
#define N_REL_C 500
#define NEDGE_C 500000
#define SCAN_BLOCKS 391   // ceil(100000/256)
#define EPB 1024          // edges per block for rel sort
#define NB_EDGE 489       // ceil(500000/1024)
#define CHUNK_B 62        // ceil(489/8)
#define MT_TOTAL 6250     // 100000/16 m-tiles, exact
#define MFMA4_GRID 512    // grid-stride m-loop
#define CVT_GRID 1563     // ceil(6250*64/256)

// ---------------- ws layout (float offsets) — 15.25M < proven 25.7M -------------------
#define OFF_WTHI  0         // Wt hi bf16 [256][128] -> 16384 f32 slots
#define OFF_WTLO  16384
#define OFF_WTR   32768     // Wtr f32 [128][128]
#define OFF_PR    49152     // Pr f32 [500][128]
#define OFF_PRH   113152    // PrH bf16 [500][128]
#define OFF_QR    145920    // qr f32 [512]
#define OFF_QS    146432    // qs f32 [100000]   (atomic accum, zeroed)
#define OFF_QD    246432    // qd f32 [100000]   (atomic accum, zeroed)
#define OFF_OSRC  346432    // offsSrc [100000]
#define OFF_DRE   446432    // drE int4 [500000] {d,r,eb,-} = 2M ints (16B-aligned)
#define OFF_PSH   2446432   // PsH bf16 [100000][128]
#define OFF_PDH   8846432   // PdH bf16 [100000][128]
// end = 15,246,432 floats = 61 MB

// ---------------- d_out entity region (12.8M f32) as time-shared scratch --------------
// Phase A (ent_cvt/ent_mfma4): EntF frag-linear bf16 [6250][2][4][64] uint4 = 12.8M slots
// Phase B (sort+rel): offsets below. src_phase finally overwrites everything.
#define DO_HSRC     0         // histSrc [100000]
#define DO_BSUM     100000    // blockSums [512]
#define DO_RELSTART 100512    // relStart [512]
#define DO_PART8    101024    // partial [8][512]
#define DO_CHUNKOFF 105120    // chunkOff [8][512]
#define DO_BLKHIST  109216    // blkHist [489][512]
#define DO_BLKOFFS  359584    // blockOffs [489][512]
#define DO_SDE      609952    // sdE int4 [500000] {s,d,eb,-} (16B-aligned)
#define DO_RELP     2609952   // relpart [4000][132] -> end 3,137,952 < 12.8M

typedef short bf16x8 __attribute__((ext_vector_type(8)));   // 8 bf16 = 16B = 4 VGPRs
typedef float f32x4  __attribute__((ext_vector_type(4)));
typedef float f32x2  __attribute__((ext_vector_type(2)));
typedef unsigned short u16x8 __attribute__((ext_vector_type(8)));

__device__ inline unsigned short bf_rne(float x) {
    unsigned int u = __float_as_uint(x);
    u += 0x7FFF + ((u >> 16) & 1);          // round-nearest-even
    return (unsigned short)(u >> 16);
}
__device__ inline float bf2f(unsigned short h) {
    return __uint_as_float(((unsigned int)h) << 16);
}
__device__ inline f32x2 bfpair(unsigned int w) {
    f32x2 r;
    r.x = __uint_as_float(w << 16);
    r.y = __uint_as_float(w & 0xFFFF0000u);
    return r;
}

// ---------------- weight prep ----------------
__global__ void prep_w(const float* __restrict__ aw, unsigned short* __restrict__ Wthi,
                       unsigned short* __restrict__ Wtlo, float* __restrict__ Wtr) {
    int idx = blockIdx.x * 256 + threadIdx.x;   // 0..49151
    if (idx < 32768) {
        int n = idx >> 7, k = idx & 127;
        float v = (n < 128) ? aw[n * 384 + k] : aw[(n - 128) * 384 + 128 + k];
        unsigned short h = bf_rne(v);
        Wthi[idx] = h;
        Wtlo[idx] = bf_rne(v - bf2f(h));
    } else if (idx < 49152) {
        int t = idx - 32768;
        int k = t >> 7, o = t & 127;
        Wtr[t] = aw[o * 384 + 256 + k];
    }
}

// ---------------- rel projection + qr epilogue ----------------
__global__ void rel_proj(const float* __restrict__ rele, const float* __restrict__ Wtr,
                         const float* __restrict__ ab, const float* __restrict__ a2w,
                         float* __restrict__ Pr, unsigned short* __restrict__ PrH,
                         float* __restrict__ qr) {
    int r = blockIdx.x;
    int o = threadIdx.x;
    float acc = ab[o];
    for (int k = 0; k < 128; ++k)
        acc = fmaf(rele[r * 128 + k], Wtr[k * 128 + o], acc);
    Pr[r * 128 + o] = acc;
    PrH[r * 128 + o] = bf_rne(acc);
    __shared__ float red[128];
    red[o] = acc * a2w[o];
    __syncthreads();
    for (int off = 64; off > 0; off >>= 1) {
        if (o < off) red[o] += red[o + off];
        __syncthreads();
    }
    if (o == 0) qr[r] = red[0];
}

// ---------------- pass 1: ent f32 -> frag-linear bf16 hi/lo ----------------
__global__ __launch_bounds__(256) void ent_cvt(const float* __restrict__ ent,
                                               uint4* __restrict__ EntF) {
    int gw = blockIdx.x * 256 + threadIdx.x;
    int mt = gw >> 6;
    if (mt >= MT_TOTAL) return;
    int lane = gw & 63;
    int row = mt * 16 + (lane & 15);
    int kb0 = (lane >> 4) * 8;
    const float* rp = ent + (size_t)row * 128;
    size_t mb = (size_t)mt * 8;
#pragma unroll
    for (int ks = 0; ks < 4; ++ks) {
        float4 a = *(const float4*)(rp + ks * 32 + kb0);
        float4 b = *(const float4*)(rp + ks * 32 + kb0 + 4);
        float f[8] = {a.x, a.y, a.z, a.w, b.x, b.y, b.z, b.w};
        union { unsigned short u[8]; uint4 v; } H, L;
#pragma unroll
        for (int j = 0; j < 8; ++j) {
            unsigned short h = bf_rne(f[j]);
            H.u[j] = h;
            L.u[j] = bf_rne(f[j] - bf2f(h));
        }
        EntF[(mb + ks) * 64 + lane] = H.v;
        EntF[(mb + 4 + ks) * 64 + lane] = L.v;
    }
}

// ---------------- pass 2: MFMA with W staged in LDS (no remat possible) ---------------
__global__ __launch_bounds__(512, 2) void ent_mfma4(const uint4* __restrict__ EntF,
                                                    const unsigned short* __restrict__ Wthi,
                                                    const unsigned short* __restrict__ Wtlo,
                                                    const float* __restrict__ a2w,
                                                    unsigned short* __restrict__ PsH,
                                                    unsigned short* __restrict__ PdH,
                                                    float* __restrict__ qs,
                                                    float* __restrict__ qd) {
    __shared__ __align__(16) char shw[131072];   // Whi [0,64K), Wlo [64K,128K)
    const int tid = threadIdx.x;

    // stage W (once per block): 8192 16B-chunks, swizzled
#pragma unroll
    for (int it = 0; it < 16; ++it) {
        int g = it * 512 + tid;          // 0..8191
        int arr = g >> 12;               // 0 = hi, 1 = lo
        int gg = g & 4095;
        int n = gg >> 4, slot = gg & 15;
        const unsigned short* srcp = (arr ? Wtlo : Wthi) + n * 128 + slot * 8;
        uint4 v = *(const uint4*)srcp;
        *(uint4*)(shw + arr * 65536 + n * 256 + ((slot ^ (n & 7)) << 4)) = v;
    }
    __syncthreads();

    const int w = tid >> 6, lane = tid & 63;
    const int l15 = lane & 15, lh = lane >> 4;
    const int n0 = w * 32;

    float a2v[2][4];
#pragma unroll
    for (int nf = 0; nf < 2; ++nf)
#pragma unroll
        for (int v = 0; v < 4; ++v)
            a2v[nf][v] = a2w[(n0 + nf * 16 + lh * 4 + v) & 127];

    const bool isPs = (w < 4);
    unsigned short* PH = isPs ? PsH : PdH;
    float* qout = isPs ? qs : qd;
    const int colbase = (n0 & 127) + lh * 4;

    // per-lane LDS offsets for this wave's two n-rows
    int nA = n0 + l15, nB = n0 + 16 + l15;
    int offA = nA * 256, offB = nB * 256;
    int swzA = (nA & 7), swzB = (nB & 7);

    const bf16x8* EB = (const bf16x8*)EntF;
    f32x4 zz = {0.f, 0.f, 0.f, 0.f};

    for (int mt = blockIdx.x; mt < MT_TOTAL; mt += MFMA4_GRID) {
        size_t mb = (size_t)mt * 512;
        bf16x8 eh[4], el[4];
#pragma unroll
        for (int ks = 0; ks < 4; ++ks) {
            eh[ks] = EB[mb + (size_t)ks * 64 + lane];
            el[ks] = EB[mb + 256 + (size_t)ks * 64 + lane];
        }
        f32x4 acc[2];
        acc[0] = zz; acc[1] = zz;
#pragma unroll
        for (int ks = 0; ks < 4; ++ks) {
            int slot = ks * 4 + lh;
            int oA = offA + (((slot ^ swzA)) << 4);
            int oB = offB + (((slot ^ swzB)) << 4);
            bf16x8 whA = *(const bf16x8*)(shw + oA);
            bf16x8 wlA = *(const bf16x8*)(shw + 65536 + oA);
            bf16x8 whB = *(const bf16x8*)(shw + oB);
            bf16x8 wlB = *(const bf16x8*)(shw + 65536 + oB);
            acc[0] = __builtin_amdgcn_mfma_f32_16x16x32_bf16(whA, eh[ks], acc[0], 0, 0, 0);
            acc[0] = __builtin_amdgcn_mfma_f32_16x16x32_bf16(whA, el[ks], acc[0], 0, 0, 0);
            acc[0] = __builtin_amdgcn_mfma_f32_16x16x32_bf16(wlA, eh[ks], acc[0], 0, 0, 0);
            acc[1] = __builtin_amdgcn_mfma_f32_16x16x32_bf16(whB, eh[ks], acc[1], 0, 0, 0);
            acc[1] = __builtin_amdgcn_mfma_f32_16x16x32_bf16(whB, el[ks], acc[1], 0, 0, 0);
            acc[1] = __builtin_amdgcn_mfma_f32_16x16x32_bf16(wlB, eh[ks], acc[1], 0, 0, 0);
        }

        int m = mt * 16 + l15;
        float qp = 0.f;
#pragma unroll
        for (int nf = 0; nf < 2; ++nf) {
            ushort4 st;
            st.x = bf_rne(acc[nf][0]);
            st.y = bf_rne(acc[nf][1]);
            st.z = bf_rne(acc[nf][2]);
            st.w = bf_rne(acc[nf][3]);
#pragma unroll
            for (int v = 0; v < 4; ++v) qp = fmaf(acc[nf][v], a2v[nf][v], qp);
            *(ushort4*)&PH[(size_t)m * 128 + colbase + nf * 16] = st;
        }
        qp += __shfl_xor(qp, 16);
        qp += __shfl_xor(qp, 32);
        if (lane < 16) unsafeAtomicAdd(&qout[m], qp);
    }
}

// ---------------- rel-key block histogram (LDS) + src global hist, int4 loads ---------
__global__ __launch_bounds__(256) void edge_hist(const int* __restrict__ src,
                                                 const int* __restrict__ rel,
                                                 int* __restrict__ histSrc,
                                                 int* __restrict__ blkHist) {
    __shared__ int lh[512];
    int tid = threadIdx.x;
    lh[tid] = 0; lh[tid + 256] = 0;
    __syncthreads();
    int e0 = blockIdx.x * EPB + tid * 4;    // NEDGE_C % 4 == 0: chunk fully in or out
    if (e0 < NEDGE_C) {
        int4 s4 = *(const int4*)&src[e0];
        int4 r4 = *(const int4*)&rel[e0];
        atomicAdd(&histSrc[s4.x], 1);
        atomicAdd(&histSrc[s4.y], 1);
        atomicAdd(&histSrc[s4.z], 1);
        atomicAdd(&histSrc[s4.w], 1);
        atomicAdd(&lh[r4.x], 1);
        atomicAdd(&lh[r4.y], 1);
        atomicAdd(&lh[r4.z], 1);
        atomicAdd(&lh[r4.w], 1);
    }
    __syncthreads();
    blkHist[blockIdx.x * 512 + tid] = lh[tid];
    blkHist[blockIdx.x * 512 + 256 + tid] = lh[tid + 256];
}

__global__ void colsum(const int* __restrict__ blkHist, int* __restrict__ partial) {
    int r = threadIdx.x;
    int k = blockIdx.x;
    int b0 = k * CHUNK_B;
    int b1 = min(b0 + CHUNK_B, NB_EDGE);
    int t = 0;
    for (int b = b0; b < b1; ++b) t += blkHist[b * 512 + r];
    partial[k * 512 + r] = t;
}

__global__ void scan512(const int* __restrict__ partial, int* __restrict__ relStart,
                        int* __restrict__ chunkOff) {
    __shared__ int a[512], b2[512];
    int tid = threadIdx.x;
    int p8[8];
    int t = 0;
#pragma unroll
    for (int k = 0; k < 8; ++k) { p8[k] = partial[k * 512 + tid]; t += p8[k]; }
    a[tid] = t;
    __syncthreads();
    int v = t;
    int* cur = a; int* nxt = b2;
    for (int off = 1; off < 512; off <<= 1) {
        int x = cur[tid] + ((tid >= off) ? cur[tid - off] : 0);
        nxt[tid] = x;
        __syncthreads();
        int* tmp = cur; cur = nxt; nxt = tmp;
    }
    int excl = cur[tid] - v;
    relStart[tid] = excl;
    int run = excl;
#pragma unroll
    for (int k = 0; k < 8; ++k) { chunkOff[k * 512 + tid] = run; run += p8[k]; }
}

__global__ void colscan(const int* __restrict__ blkHist, const int* __restrict__ chunkOff,
                        int* __restrict__ blockOffs) {
    int r = threadIdx.x;
    int k = blockIdx.x;
    int b0 = k * CHUNK_B;
    int b1 = min(b0 + CHUNK_B, NB_EDGE);
    int off = chunkOff[k * 512 + r];
    for (int b = b0; b < b1; ++b) {
        blockOffs[b * 512 + r] = off;
        off += blkHist[b * 512 + r];
    }
}

__global__ void scan_blockred(const int* __restrict__ hist, int* __restrict__ blockSums, int n) {
    __shared__ int s[256];
    int tid = threadIdx.x;
    int i = blockIdx.x * 256 + tid;
    s[tid] = (i < n) ? hist[i] : 0;
    __syncthreads();
    for (int off = 128; off > 0; off >>= 1) {
        if (tid < off) s[tid] += s[tid + off];
        __syncthreads();
    }
    if (tid == 0) blockSums[blockIdx.x] = s[0];
}

__global__ void scan_single(int* __restrict__ data, int n) {
    __shared__ int a[1024], b2[1024];
    int tid = threadIdx.x;
    int v = (tid < n) ? data[tid] : 0;
    a[tid] = v;
    __syncthreads();
    int* cur = a; int* nxt = b2;
    for (int off = 1; off < 1024; off <<= 1) {
        int x = cur[tid] + ((tid >= off) ? cur[tid - off] : 0);
        nxt[tid] = x;
        __syncthreads();
        int* t = cur; cur = nxt; nxt = t;
    }
    if (tid < n) data[tid] = cur[tid] - v;   // exclusive
}

__global__ void scan_final(const int* __restrict__ hist, const int* __restrict__ blockOffs,
                           int* __restrict__ offs, int n) {
    __shared__ int a[256], b2[256];
    int tid = threadIdx.x;
    int i = blockIdx.x * 256 + tid;
    int v = (i < n) ? hist[i] : 0;
    a[tid] = v;
    __syncthreads();
    int* cur = a; int* nxt = b2;
    for (int off = 1; off < 256; off <<= 1) {
        int x = cur[tid] + ((tid >= off) ? cur[tid - off] : 0);
        nxt[tid] = x;
        __syncthreads();
        int* t = cur; cur = nxt; nxt = t;
    }
    if (i < n) offs[i] = cur[tid] - v + blockOffs[blockIdx.x];
}

// ---------------- scatter: int4 index loads + int4 payloads {idx, idx, eb} ------------
__global__ __launch_bounds__(256) void scatter_both(const int* __restrict__ src,
                                                    const int* __restrict__ dst,
                                                    const int* __restrict__ rel,
                                                    int* __restrict__ offsSrc,
                                                    const int* __restrict__ blockOffs,
                                                    const float* __restrict__ qs,
                                                    const float* __restrict__ qd,
                                                    const float* __restrict__ qr,
                                                    const float* __restrict__ a2b,
                                                    int4* __restrict__ drE,
                                                    int4* __restrict__ sdE) {
    __shared__ int lh[512];
    int tid = threadIdx.x;
    lh[tid] = 0; lh[tid + 256] = 0;
    __syncthreads();
    float bb = a2b[0];
    const int* bo = &blockOffs[blockIdx.x * 512];
    int e0 = blockIdx.x * EPB + tid * 4;    // NEDGE_C % 4 == 0: chunk fully in or out
    if (e0 < NEDGE_C) {
        int4 s4 = *(const int4*)&src[e0];
        int4 d4 = *(const int4*)&dst[e0];
        int4 r4 = *(const int4*)&rel[e0];
        int ss[4] = {s4.x, s4.y, s4.z, s4.w};
        int dd[4] = {d4.x, d4.y, d4.z, d4.w};
        int rr[4] = {r4.x, r4.y, r4.z, r4.w};
#pragma unroll
        for (int j = 0; j < 4; ++j) {
            int s = ss[j], d = dd[j], r = rr[j];
            float b = qs[s] + qd[d] + qr[r] + bb;
            b = (b > 0.f) ? b : 0.01f * b;
            float eb = __expf(b);
            int ebi = __float_as_int(eb);
            int p = atomicAdd(&offsSrc[s], 1);
            drE[p] = make_int4(d, r, ebi, 0);
            int lr = atomicAdd(&lh[r], 1);
            sdE[bo[r] + lr] = make_int4(s, d, ebi, 0);
        }
    }
    __syncthreads();
}

// ---------------- rel phase: 8 partial blocks per relation, pk unpack -----------------
__global__ __launch_bounds__(256) void rel_phase(const unsigned short* __restrict__ PsH,
                                                 const unsigned short* __restrict__ PdH,
                                                 const int* __restrict__ relStart,
                                                 const int4* __restrict__ sdE,
                                                 float* __restrict__ relpart) {
    int r = blockIdx.x >> 3;
    int p = blockIdx.x & 7;
    int start = relStart[r];
    int end = relStart[r + 1];
    int tid = threadIdx.x;
    int w = tid >> 6;
    int h = (tid >> 5) & 1;
    int l = tid & 31;
    int slot = p * 8 + w * 2 + h;
    f32x2 acc0 = {0.f, 0.f}, acc1 = {0.f, 0.f};
    float ebs = 0.f;
    for (int i = start + slot; i < end; i += 64) {
        int4 sd = sdE[i];
        int s = sd.x, d = sd.y;
        float eb = __int_as_float(sd.z);
        uint2 pw = *(const uint2*)&PsH[(size_t)s * 128 + l * 4];
        uint2 dw = *(const uint2*)&PdH[(size_t)d * 128 + l * 4];
        f32x2 ebp = {eb, eb};
        acc0 = ebp * (bfpair(pw.x) + bfpair(dw.x)) + acc0;
        acc1 = ebp * (bfpair(pw.y) + bfpair(dw.y)) + acc1;
        ebs += eb;
    }
    __shared__ float vred[8][128];
    __shared__ float sred[8];
    int sub = w * 2 + h;
    float4 accv = make_float4(acc0.x, acc0.y, acc1.x, acc1.y);
    *(float4*)&vred[sub][l * 4] = accv;
    if (l == 0) sred[sub] = ebs;
    __syncthreads();
    if (tid < 128) {
        float v = 0.f;
#pragma unroll
        for (int k2 = 0; k2 < 8; ++k2) v += vred[k2][tid];
        float e = 0.f;
#pragma unroll
        for (int k2 = 0; k2 < 8; ++k2) e += sred[k2];
        int pi = r * 8 + p;
        relpart[pi * 132 + tid] = v;
        if (tid == 0) relpart[pi * 132 + 128] = e;
    }
}

__global__ void rel_fin(const float* __restrict__ relpart, const float* __restrict__ Pr,
                        const int* __restrict__ relStart, float* __restrict__ outRel) {
    int r = blockIdx.x;
    int o = threadIdx.x;
    float v = 0.f, e = 0.f;
#pragma unroll
    for (int p = 0; p < 8; ++p) {
        v += relpart[(r * 8 + p) * 132 + o];
        e += relpart[(r * 8 + p) * 132 + 128];
    }
    float cnt = (float)(relStart[r + 1] - relStart[r]);
    float h = (v + e * Pr[r * 128 + o]) / fmaxf(cnt, 1.f);
    outRel[r * 128 + o] = (h > 0.f) ? h : (__expf(h) - 1.f);
}

// ---------------- src phase: 4 edges in flight, int4 record, pk unpack, fast exp ------
__global__ __launch_bounds__(256) void src_phase(const unsigned short* __restrict__ PsH,
                                                 const unsigned short* __restrict__ PdH,
                                                 const unsigned short* __restrict__ PrH,
                                                 const int* __restrict__ offsSrc,
                                                 const int4* __restrict__ drE,
                                                 float* __restrict__ out) {
    int wid = (blockIdx.x * 256 + threadIdx.x) >> 6;
    if (wid >= N_ENT_C) return;
    int lane = threadIdx.x & 63;
    int g = lane >> 4, l = lane & 15;   // 4 groups x 16 lanes; lane covers cols l*8..l*8+7
    int s = wid;
    int start = (s == 0) ? 0 : offsSrc[s - 1];
    int end = offsSrc[s];
    float* dstp = &out[(size_t)s * 128];
    if (end == start) {
        if (g == 0) {
            *(float4*)&dstp[l * 8] = make_float4(0.f, 0.f, 0.f, 0.f);
            *(float4*)&dstp[l * 8 + 4] = make_float4(0.f, 0.f, 0.f, 0.f);
        }
        return;
    }
    f32x2 accp[4];
#pragma unroll
    for (int j = 0; j < 4; ++j) accp[j] = (f32x2){0.f, 0.f};
    float ebs = 0.f;
    for (int i = start + g; i < end; i += 4) {
        int4 er = drE[i];
        int d = er.x, r = er.y;
        float eb = __int_as_float(er.z);
        uint4 dw = *(const uint4*)&PdH[(size_t)d * 128 + l * 8];
        uint4 rw = *(const uint4*)&PrH[(size_t)r * 128 + l * 8];
        f32x2 ebp = {eb, eb};
        accp[0] = ebp * (bfpair(dw.x) + bfpair(rw.x)) + accp[0];
        accp[1] = ebp * (bfpair(dw.y) + bfpair(rw.y)) + accp[1];
        accp[2] = ebp * (bfpair(dw.z) + bfpair(rw.z)) + accp[2];
        accp[3] = ebp * (bfpair(dw.w) + bfpair(rw.w)) + accp[3];
        ebs += eb;
    }
    float a8[8] = {accp[0].x, accp[0].y, accp[1].x, accp[1].y,
                   accp[2].x, accp[2].y, accp[3].x, accp[3].y};
#pragma unroll
    for (int j = 0; j < 8; ++j) {
        a8[j] += __shfl_xor(a8[j], 16);
        a8[j] += __shfl_xor(a8[j], 32);
    }
    ebs += __shfl_xor(ebs, 16);
    ebs += __shfl_xor(ebs, 32);
    if (g == 0) {
        float inv = 1.f / ebs;
        u16x8 ps = *(const u16x8*)&PsH[(size_t)s * 128 + l * 8];
        float h[8];
#pragma unroll
        for (int j = 0; j < 8; ++j) {
            float x = bf2f(ps[j]) + a8[j] * inv;
            h[j] = (x > 0.f) ? x : (__expf(x) - 1.f);
        }
        *(float4*)&dstp[l * 8]     = make_float4(h[0], h[1], h[2], h[3]);
        *(float4*)&dstp[l * 8 + 4] = make_float4(h[4], h[5], h[6], h[7]);
    }
}

extern "C" void kernel_launch(void* const* d_in, const int* in_sizes, int n_in,
                              void* d_out, int out_size, void* d_ws, size_t ws_size,
                              hipStream_t stream) {
    const float* ent  = (const float*)d_in[0];
    const float* rele = (const float*)d_in[1];
    const float* aw   = (const float*)d_in[2];
    const float* ab   = (const float*)d_in[3];
    const float* a2w  = (const float*)d_in[4];
    const float* a2b  = (const float*)d_in[5];
    const int* src    = (const int*)d_in[6];
    const int* dst    = (const int*)d_in[7];
    const int* rel    = (const int*)d_in[8];
    float* out = (float*)d_out;

    float* ws = (float*)d_ws;
    unsigned short* Wthi = (unsigned short*)(ws + OFF_WTHI);
    unsigned short* Wtlo = (unsigned short*)(ws + OFF_WTLO);
    float* Wtr = ws + OFF_WTR;
    float* Pr  = ws + OFF_PR;
    unsigned short* PrH = (unsigned short*)(ws + OFF_PRH);
    float* qr  = ws + OFF_QR;
    float* qs  = ws + OFF_QS;
    float* qd  = ws + OFF_QD;
    int* offsSrc = (int*)(ws + OFF_OSRC);
    int4* drE    = (int4*)(ws + OFF_DRE);
    unsigned short* PsH = (unsigned short*)(ws + OFF_PSH);
    unsigned short* PdH = (unsigned short*)(ws + OFF_PDH);

    int* dI = (int*)d_out;
    uint4* EntF   = (uint4*)d_out;            // phase A only
    int* histSrc  = dI + DO_HSRC;
    int* bsum     = dI + DO_BSUM;
    int* relStart = dI + DO_RELSTART;
    int* part8    = dI + DO_PART8;
    int* chunkOff = dI + DO_CHUNKOFF;
    int* blkHist  = dI + DO_BLKHIST;
    int* blockOffs= dI + DO_BLKOFFS;
    int4* sdE     = (int4*)(dI + DO_SDE);
    float* relpart = (float*)dI + DO_RELP;

    hipMemsetAsync(ws + OFF_QR, 0, (size_t)(OFF_OSRC - OFF_QR) * sizeof(float), stream);

    prep_w<<<192, 256, 0, stream>>>(aw, Wthi, Wtlo, Wtr);
    rel_proj<<<N_REL_C, 128, 0, stream>>>(rele, Wtr, ab, a2w, Pr, PrH, qr);
    ent_cvt<<<CVT_GRID, 256, 0, stream>>>(ent, EntF);
    ent_mfma4<<<MFMA4_GRID, 512, 0, stream>>>(EntF, Wthi, Wtlo, a2w, PsH, PdH, qs, qd);

    // EntF now dead -> reuse d_out entity region as sort scratch
    hipMemsetAsync(histSrc, 0, (size_t)N_ENT_C * sizeof(int), stream);
    edge_hist<<<NB_EDGE, 256, 0, stream>>>(src, rel, histSrc, blkHist);
    colsum<<<8, 512, 0, stream>>>(blkHist, part8);
    scan512<<<1, 512, 0, stream>>>(part8, relStart, chunkOff);
    colscan<<<8, 512, 0, stream>>>(blkHist, chunkOff, blockOffs);
    scan_blockred<<<SCAN_BLOCKS, 256, 0, stream>>>(histSrc, bsum, N_ENT_C);
    scan_single<<<1, 1024, 0, stream>>>(bsum, SCAN_BLOCKS);
    scan_final<<<SCAN_BLOCKS, 256, 0, stream>>>(histSrc, bsum, offsSrc, N_ENT_C);
    scatter_both<<<NB_EDGE, 256, 0, stream>>>(src, dst, rel, offsSrc, blockOffs,
                                              qs, qd, qr, a2b, drE, sdE);

    rel_phase<<<N_REL_C * 8, 256, 0, stream>>>(PsH, PdH, relStart, sdE, relpart);
    rel_fin<<<N_REL_C, 128, 0, stream>>>(relpart, Pr, relStart, out + (size_t)N_ENT_C * 128);

    src_phase<<<(N_ENT_C + 3) / 4, 256, 0, stream>>>(PsH, PdH, PrH, offsSrc, drE, out);
}